// Round 9
// baseline (470.924 us; speedup 1.0000x reference)
//
#include <hip/hip_runtime.h>

#define S_ 1024
#define M_ 1024
#define T_ 2048
#define B_ 4
#define H_ 16
#define DM_ 1024
#define DH_ 64

typedef __attribute__((ext_vector_type(8))) short s16x8;
typedef __attribute__((ext_vector_type(16))) float f32x16;

__device__ __forceinline__ unsigned short f2b(float x){
  unsigned int u = __float_as_uint(x);
  u = (u + 0x7fffu + ((u>>16)&1u)) >> 16;
  return (unsigned short)u;
}
__device__ __forceinline__ float b2f(unsigned short h){
  return __uint_as_float(((unsigned int)h)<<16);
}
__device__ __forceinline__ uint4 pack8(const float* v){
  uint4 o;
  o.x = (unsigned)f2b(v[0]) | ((unsigned)f2b(v[1])<<16);
  o.y = (unsigned)f2b(v[2]) | ((unsigned)f2b(v[3])<<16);
  o.z = (unsigned)f2b(v[4]) | ((unsigned)f2b(v[5])<<16);
  o.w = (unsigned)f2b(v[6]) | ((unsigned)f2b(v[7])<<16);
  return o;
}
__device__ __forceinline__ void glds16(const unsigned short* g, unsigned short* l){
  __builtin_amdgcn_global_load_lds((const __attribute__((address_space(1))) void*)g,
                                   (__attribute__((address_space(3))) void*)l, 16, 0, 0);
}

// raw barriers:
//   BAR_L   waits only LDS ops (glds prefetches stay in flight)
//   BAR_VL  drains vmcnt fully
//   BAR_V6L counted drain: waits for the 2 OLDEST vmem ops (VT of this iter),
//           leaves the 6 newer K/R(j+1) prefetches in flight (T4).
#define BAR_L()   asm volatile("s_waitcnt lgkmcnt(0)\ns_barrier" ::: "memory")
#define BAR_VL()  asm volatile("s_waitcnt vmcnt(0) lgkmcnt(0)\ns_barrier" ::: "memory")
#define BAR_V6L() asm volatile("s_waitcnt vmcnt(6) lgkmcnt(0)\ns_barrier" ::: "memory")

// ---------------- fused cast kernel ----------------
__global__ __launch_bounds__(256) void cast_all(
    const float* __restrict__ mem, const float* __restrict__ x,
    const float* __restrict__ pos, const float* __restrict__ wqkv,
    const float* __restrict__ wrel, const float* __restrict__ wo,
    unsigned short* __restrict__ c16, unsigned short* __restrict__ pos16,
    unsigned short* __restrict__ wq16, unsigned short* __restrict__ wr16,
    unsigned short* __restrict__ wo16)
{
  int u = blockIdx.x*256 + threadIdx.x;
  const float* s; unsigned short* d;
  if (u < 1048576)      { s = (u < 524288) ? mem + (size_t)u*8 : x + (size_t)(u-524288)*8;
                          d = c16 + (size_t)u*8; }
  else if (u < 2097152) { int v = u - 1048576; s = pos  + (size_t)v*8; d = pos16 + (size_t)v*8; }
  else if (u < 2490368) { int v = u - 2097152; s = wqkv + (size_t)v*8; d = wq16  + (size_t)v*8; }
  else if (u < 2621440) { int v = u - 2490368; s = wrel + (size_t)v*8; d = wr16  + (size_t)v*8; }
  else                  { int v = u - 2621440; s = wo   + (size_t)v*8; d = wo16  + (size_t)v*8; }
  float4 x0 = *(const float4*)s;
  float4 x1 = *(const float4*)(s+4);
  float f[8] = {x0.x,x0.y,x0.z,x0.w,x1.x,x1.y,x1.z,x1.w};
  *(uint4*)d = pack8(f);
}

// ---------------- GEMM: C[M][N] = A[M][K] @ B[N][K]^T  (bf16 in, NT) ----------------
__global__ __launch_bounds__(256) void gemm_nt(const unsigned short* __restrict__ A,
    const unsigned short* __restrict__ Bw, void* __restrict__ Cout,
    const float* __restrict__ res, int Ntot, int K, int mode)
{
  __shared__ __align__(16) unsigned short a_s[128*64];
  __shared__ __align__(16) unsigned short b_s[128*64];
  const int tid = threadIdx.x;
  const int lane = tid & 63, wave = tid >> 6;
  const int wr = wave >> 1, wc = wave & 1;
  const long m0 = (long)blockIdx.y * 128, n0 = (long)blockIdx.x * 128;
  f32x16 acc[2][2];
  for (int qa=0;qa<2;qa++) for(int qb=0;qb<2;qb++) for (int e=0;e<16;e++) acc[qa][qb][e]=0.f;
  int srow[4], scol[4];
  for (int c = 0; c < 4; c++) {
    int ch = c*256 + tid;
    srow[c] = ch >> 3;
    scol[c] = (((ch & 7) ^ (srow[c] & 7))) * 8;
  }
  for (int k0 = 0; k0 < K; k0 += 64) {
    for (int c = 0; c < 4; c++) {
      int ch = c*256 + tid;
      glds16(&A[(size_t)(m0+srow[c])*K + k0 + scol[c]], &a_s[ch*8]);
      glds16(&Bw[(size_t)(n0+srow[c])*K + k0 + scol[c]], &b_s[ch*8]);
    }
    __syncthreads();
    for (int ks = 0; ks < 4; ks++) {
      const int kb = ks*2 + (lane>>5);
      s16x8 af[2], bf[2];
      for (int q = 0; q < 2; q++) {
        int ra = wr*64 + q*32 + (lane&31);
        int rb = wc*64 + q*32 + (lane&31);
        af[q] = *(const s16x8*)&a_s[ra*64 + ((kb ^ (ra&7))<<3)];
        bf[q] = *(const s16x8*)&b_s[rb*64 + ((kb ^ (rb&7))<<3)];
      }
      for (int qr=0;qr<2;qr++)
        for (int qc2=0;qc2<2;qc2++)
          acc[qr][qc2] = __builtin_amdgcn_mfma_f32_32x32x16_bf16(af[qr], bf[qc2], acc[qr][qc2], 0,0,0);
    }
    __syncthreads();
  }
  for (int qr=0;qr<2;qr++)
    for (int qc2=0;qc2<2;qc2++)
      for (int e=0;e<16;e++){
        long row = m0 + wr*64 + qr*32 + (e&3) + 8*(e>>2) + 4*(lane>>5);
        long col = n0 + wc*64 + qc2*32 + (lane&31);
        size_t o = (size_t)row*Ntot + col;
        if (mode == 0) ((unsigned short*)Cout)[o] = f2b(acc[qr][qc2][e]);
        else           ((float*)Cout)[o] = acc[qr][qc2][e] + res[o];
      }
}

// ---------------- scatter: q + biases, per-head layout ----------------
__global__ __launch_bounds__(256) void scatter_quv(const unsigned short* __restrict__ qkvo,
   const float* __restrict__ u, const float* __restrict__ v,
   unsigned short* __restrict__ QU, unsigned short* __restrict__ QV)
{
  int gid = blockIdx.x*256 + threadIdx.x;   // B*H*S*8 = 524288
  int d0 = (gid & 7) * 8;
  int i  = (gid >> 3) & (S_-1);
  int bh = gid >> 13;
  int b = bh >> 4, h = bh & 15;
  size_t src = (size_t)((M_+i)*B_ + b)*3072 + h*64 + d0;
  uint4 q8 = *(const uint4*)&qkvo[src];
  float f[8];
  f[0]=b2f(q8.x&0xffff); f[1]=b2f(q8.x>>16); f[2]=b2f(q8.y&0xffff); f[3]=b2f(q8.y>>16);
  f[4]=b2f(q8.z&0xffff); f[5]=b2f(q8.z>>16); f[6]=b2f(q8.w&0xffff); f[7]=b2f(q8.w>>16);
  float fu[8], fv[8];
  for (int e=0;e<8;e++){ fu[e] = f[e] + u[h*64+d0+e]; fv[e] = f[e] + v[h*64+d0+e]; }
  size_t dst = ((size_t)bh*S_ + i)*64 + d0;
  *(uint4*)&QU[dst] = pack8(fu);
  *(uint4*)&QV[dst] = pack8(fv);
}

// ---------------- scatter_vt: VT[bh][d][t] = V[t][b][h][d] (LDS transpose) ----------------
__global__ __launch_bounds__(256) void scatter_vt(const unsigned short* __restrict__ qkvo,
    unsigned short* __restrict__ VT)
{
  __shared__ __align__(16) unsigned short v_s[64*72];
  const int tid = threadIdx.x;
  const int bh = blockIdx.x, b = bh>>4, h = bh&15;
  const int t0 = blockIdx.y*64;
  const unsigned short* Vg = qkvo + (size_t)b*3072 + 2048 + h*64;
  for (int c=0;c<2;c++){
    int ch = c*256 + tid;
    int r = ch>>3, off = (ch&7)*8;
    *(uint4*)&v_s[r*72+off] = *(const uint4*)&Vg[(size_t)(t0+r)*12288 + off];
  }
  __syncthreads();
  for (int c=0;c<2;c++){
    int ch = c*256 + tid;
    int d = ch>>3, toff = (ch&7)*8;
    unsigned short vals[8];
    for (int e=0;e<8;e++) vals[e] = v_s[(toff+e)*72 + d];
    uint4 pk;
    pk.x = (unsigned)vals[0] | ((unsigned)vals[1]<<16);
    pk.y = (unsigned)vals[2] | ((unsigned)vals[3]<<16);
    pk.z = (unsigned)vals[4] | ((unsigned)vals[5]<<16);
    pk.w = (unsigned)vals[6] | ((unsigned)vals[7]<<16);
    *(uint4*)&VT[((size_t)bh*64 + d)*T_ + t0 + toff] = pk;
  }
}

// ---------------- fused attention v13 ----------------
// v13 = v12 with barrier B2 removed via K/R double-buffering:
//   * k_s[2], rg_s[2]: prefetch K/R(j+1) targets buf[cur^1], reads come from
//     buf[cur] -> no WAR hazard -> the B2 barrier (all-wave LDS-read drain
//     before prefetch) is deleted. 2 barriers/iter (cls0/2).
//   * K/R(j+1) issue moves to the TOP of the iteration (right after VT(j)),
//     ~2x more latency cover; cls1 no longer defers R(j+1) (wrap uses buf[cur]).
//   * vmcnt counting unchanged: VT(j) is always the oldest pair -> B3's
//     vmcnt(6) drains exactly VT; last iter full-drains.
// LDS: qv 9360 + k 2x8192 + vt 8192 + rg 2x16384 + p 8192 + l 256 = 75152 B
//   -> still 2 blocks/CU. Registers ~126 at (256,2) (cap 256; r6/r7 proved
//   (256,3)'s ~170 cap can never fit the 80-reg accumulator footprint).
__global__ __launch_bounds__(256,2) void flash_attn4(
    const unsigned short* __restrict__ QU, const unsigned short* __restrict__ QV,
    const unsigned short* __restrict__ qkvo, const unsigned short* __restrict__ VT,
    const unsigned short* __restrict__ relo, unsigned short* __restrict__ AV)
{
  __shared__ __align__(16) unsigned short qv_s[65*72];
  __shared__ __align__(16) unsigned short k_s [2][64*64];   // XOR-64, double-buffered
  __shared__ __align__(16) unsigned short vt_s[64*64];      // XOR-64, single buffer
  __shared__ __align__(16) unsigned short rg_s[2][128*64];  // R window, double-buffered
  __shared__ __align__(16) unsigned short p_s [64*64];      // QU staging, then P (XOR-64)
  __shared__ float l_s[64];

  const int tid = threadIdx.x, lane = tid&63, wave = tid>>6;
  const int bh = blockIdx.x, b = bh>>4, h = bh&15;
  const int i0 = blockIdx.y*64;
  const int qr = wave>>1, qc = wave&1;
  const int hi = lane>>5, ll = lane&31;
  const unsigned short* QUb = QU + (size_t)bh*S_*DH_;
  const unsigned short* QVb = QV + (size_t)bh*S_*DH_;
  const unsigned short* Kg  = qkvo + (size_t)b*3072 + 1024 + h*64;   // + t*12288
  const unsigned short* VTb = VT + (size_t)bh*64*T_;
  const unsigned short* Rg  = relo + (size_t)b*1024 + h*64;          // + t*4096

  // per-thread staging geometry (2-chunk tiles: K, VT)
  const int s0r = tid>>3,        s0c = (((tid&7)       ^ (s0r&7)))*8;
  const int s1r = (256+tid)>>3,  s1c = ((((256+tid)&7) ^ (s1r&7)))*8;

  // ---- prologue: DMA K(0)->k_s[0], R(0)->rg_s[0]; stage QU->p_s, QV->qv_s ----
  glds16(&Kg [(size_t)(0+s0r)*12288 + s0c], &k_s[0][(size_t)tid*8]);
  glds16(&Kg [(size_t)(0+s1r)*12288 + s1c], &k_s[0][(size_t)(256+tid)*8]);
  {
    const int wb0 = 0 - i0 + 960;    // j0=0 is always cls 0
    for (int c=0;c<4;c++){
      int ch = c*256+tid; int rr = ch>>3, off = ch&7;
      int t = wb0 + rr; t = t < 0 ? 0 : (t > T_-1 ? T_-1 : t);
      glds16(&Rg[(size_t)t*4096 + ((off ^ (rr&7)))*8], &rg_s[0][(size_t)ch*8]);
    }
  }
  for (int c=0;c<2;c++){
    int ch = c*256+tid; int row = ch>>3, off=(ch&7);
    *(uint4*)&p_s[row*64 + ((off ^ (row&7))<<3)] = *(const uint4*)&QUb[(size_t)(i0+row)*64 + off*8];
    *(uint4*)&qv_s[row*72+off*8] = *(const uint4*)&QVb[(size_t)(i0+row)*64 + off*8];
  }
  if (tid < 8) {
    int rr = i0 + 64; if (rr > S_-1) rr = S_-1;
    *(uint4*)&qv_s[64*72 + tid*8] = *(const uint4*)&QVb[(size_t)rr*64 + tid*8];
  }
  BAR_L();   // QU/QV plain stores visible

  // ---- Q-hoist: j-invariant A-fragments into registers (32 VGPRs) ----
  s16x8 qur0, qur1, qur2, qur3;     // QU row qr*32+ll (from p_s XOR-64)
  s16x8 qv00, qv01, qv02, qv03;     // QV row qr*32+ll (shift 0)
  {
    const int rq = qr*32 + ll;
    qur0 = *(const s16x8*)&p_s[rq*64 + (((0*2+hi) ^ (rq&7))<<3)];
    qur1 = *(const s16x8*)&p_s[rq*64 + (((1*2+hi) ^ (rq&7))<<3)];
    qur2 = *(const s16x8*)&p_s[rq*64 + (((2*2+hi) ^ (rq&7))<<3)];
    qur3 = *(const s16x8*)&p_s[rq*64 + (((3*2+hi) ^ (rq&7))<<3)];
    const int ro = rq*72 + hi*8;
    qv00 = *(const s16x8*)&qv_s[ro +  0];
    qv01 = *(const s16x8*)&qv_s[ro + 16];
    qv02 = *(const s16x8*)&qv_s[ro + 32];
    qv03 = *(const s16x8*)&qv_s[ro + 48];
  }
  // (no barrier here: the first loop-top BAR_VL drains K/R(0) vmem and each
  //  wave's hoist lgkm reads before gather(0) can overwrite p_s)

  s16x8 ones;
  for (int e=0;e<8;e++) ones[e] = (short)0x3F80;   // bf16 1.0

  f32x16 acc_o, acc_l;
  for (int e=0;e<16;e++){ acc_o[e]=0.f; acc_l[e]=0.f; }

  const int col = qc*32 + ll;
  const int cbase = (qc - qr + 1) * 32;   // wave's band-quad column base

  int cur = 0;
  for (int j0 = 0; j0 < T_; j0 += 64) {
    const int jdmax = j0 + 63 - i0;
    const int jdmin = j0 - 63 - i0;
    const int cls = (jdmax <= 1024) ? 0 : ((jdmin >= 1026) ? 2 : 1);
    const int jn = j0 + 64;
    unsigned short* kc = &k_s[cur][0];
    unsigned short* rc = &rg_s[cur][0];
    unsigned short* kn = &k_s[cur^1][0];
    unsigned short* rn = &rg_s[cur^1][0];

    BAR_VL();                  // B1: PV(j-1)/hoist lgkm done; K(j)/R(j) landed

    // stage VT(j) FIRST (oldest vmem pair -> B3's counted drain targets it)
    glds16(&VTb[(size_t)s0r*T_ + j0 + s0c], &vt_s[(size_t)tid*8]);
    glds16(&VTb[(size_t)s1r*T_ + j0 + s1c], &vt_s[(size_t)(256+tid)*8]);
    // prefetch K/R(j+1) into the other buffers (no WAR: reads use buf[cur])
    if (jn < T_) {
      glds16(&Kg[(size_t)(jn+s0r)*12288 + s0c], &kn[(size_t)tid*8]);
      glds16(&Kg[(size_t)(jn+s1r)*12288 + s1c], &kn[(size_t)(256+tid)*8]);
      const int jdmaxn = jn + 63 - i0;
      const int jdminn = jn - 63 - i0;
      const int clsn = (jdmaxn <= 1024) ? 0 : ((jdminn >= 1026) ? 2 : 1);
      const int wbn = (clsn == 2) ? (jn - i0 - 1089) : (jn - i0 + 960);
      for (int c=0;c<4;c++){
        int ch = c*256+tid; int rr = ch>>3, off = ch&7;
        int t = wbn + rr; t = t < 0 ? 0 : (t > T_-1 ? T_-1 : t);
        glds16(&Rg[(size_t)t*4096 + ((off ^ (rr&7)))*8], &rn[(size_t)ch*8]);
      }
    }

    // band A-operand: hoisted shift-0 regs, or LDS shift-1 rows for cls2
    s16x8 av0, av1, av2, av3;
    if (cls == 2) {
      const int ro1 = (qr*32+ll+1)*72 + hi*8;
      av0 = *(const s16x8*)&qv_s[ro1 +  0];
      av1 = *(const s16x8*)&qv_s[ro1 + 16];
      av2 = *(const s16x8*)&qv_s[ro1 + 32];
      av3 = *(const s16x8*)&qv_s[ro1 + 48];
    } else {
      av0 = qv00; av1 = qv01; av2 = qv02; av3 = qv03;
    }

    // band GEMM: the wave's OWN 2 quads at cbase (kept in registers)
    f32x16 gacc0, gacc1;
    for (int e=0;e<16;e++){ gacc0[e]=0.f; gacc1[e]=0.f; }
    __builtin_amdgcn_s_setprio(1);
#define BANDK(KS, AV) { \
      int kb = KS*2 + hi; \
      { int br = cbase + ll; \
        s16x8 bb = *(const s16x8*)&rc[br*64 + ((kb ^ (br&7))<<3)]; \
        gacc0 = __builtin_amdgcn_mfma_f32_32x32x16_bf16(AV, bb, gacc0, 0,0,0); } \
      { int br = cbase + 32 + ll; \
        s16x8 bb = *(const s16x8*)&rc[br*64 + ((kb ^ (br&7))<<3)]; \
        gacc1 = __builtin_amdgcn_mfma_f32_32x32x16_bf16(AV, bb, gacc1, 0,0,0); } }
    BANDK(0, av0) BANDK(1, av1) BANDK(2, av2) BANDK(3, av3)

    // AC quad (hoisted qur, kc in XOR-64 layout)
    f32x16 acc;
    for (int e=0;e<16;e++) acc[e]=0.f;
#define ACK(KS, AU) { \
      int kb = KS*2 + hi; \
      int rbk = qc*32 + ll; \
      s16x8 bq = *(const s16x8*)&kc[rbk*64 + ((kb ^ (rbk&7))<<3)]; \
      acc = __builtin_amdgcn_mfma_f32_32x32x16_bf16(AU, bq, acc, 0,0,0); }
    ACK(0, qur0) ACK(1, qur1) ACK(2, qur2) ACK(3, qur3)
    __builtin_amdgcn_s_setprio(0);

    // in-register gather (select-then-permute, 16 bperm) + exp -> P (XOR-64)
    for (int e=0;e<16;e++){
      int rm = 4*hi + (e&3) + 8*(e>>2);     // r - qr*32
      int r  = qr*32 + rm;
      int jd = j0 + col - (i0 + r);
      int tl = (ll + rm + 1) & 31;          // target lane fed by this source
      float sel = (tl > rm) ? gacc1[e] : gacc0[e];
      int li = ((((ll - rm + 31) & 31) | (hi<<5)) << 2);
      float bd = __uint_as_float((unsigned)__builtin_amdgcn_ds_bpermute(li, (int)__float_as_uint(sel)));
      if (jd == 1025) bd = 0.f;
      float p = __expf((acc[e] + bd) * 0.125f);
      if (!(cls == 1 && jd >= 1026))
        p_s[r*64 + (((col>>3) ^ (r&7))<<3) + (col&7)] = f2b(p);
    }

    if (cls == 1) {
      BAR_L();                 // C1: all waves' band reads of rc done
      // stage wrap R window into rc (dead after band)
      const int wb2 = j0 - i0 - 1089;
      for (int c=0;c<4;c++){
        int ch = c*256+tid; int rr = ch>>3, off = ch&7;
        int t = wb2 + rr; t = t < 0 ? 0 : (t > T_-1 ? T_-1 : t);
        glds16(&Rg[(size_t)t*4096 + ((off ^ (rr&7)))*8], &rc[(size_t)ch*8]);
      }
      BAR_VL();                // C2: wrap R landed (drains VT/K/R(j+1) too; 1x per block)
      f32x16 g2a, g2b;
      for (int e=0;e<16;e++){ g2a[e]=0.f; g2b[e]=0.f; }
      __builtin_amdgcn_s_setprio(1);
#define BANDW(KS) { \
        int kb = KS*2 + hi; \
        const int ro1 = (qr*32+ll+1)*72 + hi*8; \
        s16x8 a = *(const s16x8*)&qv_s[ro1 + KS*16]; \
        { int br = cbase + ll; \
          s16x8 bb = *(const s16x8*)&rc[br*64 + ((kb ^ (br&7))<<3)]; \
          g2a = __builtin_amdgcn_mfma_f32_32x32x16_bf16(a, bb, g2a, 0,0,0); } \
        { int br = cbase + 32 + ll; \
          s16x8 bb = *(const s16x8*)&rc[br*64 + ((kb ^ (br&7))<<3)]; \
          g2b = __builtin_amdgcn_mfma_f32_32x32x16_bf16(a, bb, g2b, 0,0,0); } }
      BANDW(0) BANDW(1) BANDW(2) BANDW(3)
      __builtin_amdgcn_s_setprio(0);
      for (int e=0;e<16;e++){
        int rm = 4*hi + (e&3) + 8*(e>>2);
        int r  = qr*32 + rm;
        int jd = j0 + col - (i0 + r);
        int tl = (ll + rm + 1) & 31;
        float sel = (tl > rm) ? g2b[e] : g2a[e];
        int li = ((((ll - rm + 31) & 31) | (hi<<5)) << 2);
        float bd = __uint_as_float((unsigned)__builtin_amdgcn_ds_bpermute(li, (int)__float_as_uint(sel)));
        float p = __expf((acc[e] + bd) * 0.125f);
        if (jd >= 1026)
          p_s[r*64 + (((col>>3) ^ (r&7))<<3) + (col&7)] = f2b(p);
      }
    }

    // B3: P visible; VT(j) landed (counted: K/R(j+1) stay in flight).
    // cls1 already fully drained at C2 -> vmcnt(6) is a no-op there.
    if (jn < T_) { BAR_V6L(); } else { BAR_VL(); }

    // PV quad + MFMA rowsum (A-fragments from p_s XOR-64)
    __builtin_amdgcn_s_setprio(1);
    for (int ks=0; ks<4; ks++){
      int kb = ks*2 + hi;
      int rv = qr*32 + ll, rbv = qc*32 + ll;
      s16x8 a  = *(const s16x8*)&p_s[rv*64 + ((kb ^ (rv&7))<<3)];
      s16x8 bv = *(const s16x8*)&vt_s[rbv*64 + ((kb ^ (rbv&7))<<3)];
      acc_o = __builtin_amdgcn_mfma_f32_32x32x16_bf16(a, bv, acc_o, 0,0,0);
      acc_l = __builtin_amdgcn_mfma_f32_32x32x16_bf16(a, ones, acc_l, 0,0,0);
    }
    __builtin_amdgcn_s_setprio(0);
    cur ^= 1;
    // no trailing barrier: loop-top B1 orders everything
  }

  // epilogue: l from acc_l (every lane's acc_l[e] = rowsum of row r)
  if (qc == 0 && ll == 0) {
    for (int e=0;e<16;e++){
      int r = qr*32 + 4*hi + (e&3) + 8*(e>>2);
      l_s[r] = acc_l[e];
    }
  }
  BAR_L();
  for (int e=0;e<16;e++){
    int r = qr*32 + 4*hi + (e&3) + 8*(e>>2);
    float oo = acc_o[e] / l_s[r];
    AV[ ((size_t)(i0+r)*B_ + b)*(H_*DH_) + h*DH_ + col ] = f2b(oo);
  }
#undef BANDK
#undef ACK
#undef BANDW
}

// ---------------- LayerNorm ----------------
__global__ __launch_bounds__(256) void ln_kernel(const float* __restrict__ y,
    const float* __restrict__ g, const float* __restrict__ be, float* __restrict__ o)
{
  __shared__ float red[8];
  int row = blockIdx.x, tid = threadIdx.x;
  const float* yr = y + (size_t)row*DM_;
  float v[4];
  for (int e=0;e<4;e++) v[e] = yr[tid + 256*e];
  float s = v[0]+v[1]+v[2]+v[3];
  for (int off=32; off>0; off>>=1) s += __shfl_down(s, off, 64);
  if ((tid&63)==0) red[tid>>6] = s;
  __syncthreads();
  if (tid==0) red[4] = red[0]+red[1]+red[2]+red[3];
  __syncthreads();
  float mu = red[4] * (1.f/DM_);
  __syncthreads();
  float q = 0.f;
  for (int e=0;e<4;e++){ float d = v[e]-mu; q += d*d; }
  for (int off=32; off>0; off>>=1) q += __shfl_down(q, off, 64);
  if ((tid&63)==0) red[tid>>6] = q;
  __syncthreads();
  if (tid==0) red[4] = red[0]+red[1]+red[2]+red[3];
  __syncthreads();
  float rstd = rsqrtf(red[4]*(1.f/DM_) + 1e-5f);
  for (int e=0;e<4;e++){
    int c = tid + 256*e;
    o[(size_t)row*DM_ + c] = g[c]*(v[e]-mu)*rstd + be[c];
  }
}

// ---------------- launch ----------------
extern "C" void kernel_launch(void* const* d_in, const int* in_sizes, int n_in,
                              void* d_out, int out_size, void* d_ws, size_t ws_size,
                              hipStream_t stream)
{
  const float* x    = (const float*)d_in[0];
  const float* mem  = (const float*)d_in[1];
  const float* pos  = (const float*)d_in[2];
  const float* pbu  = (const float*)d_in[3];
  const float* pbv  = (const float*)d_in[4];
  const float* wqkv = (const float*)d_in[5];
  const float* wrel = (const float*)d_in[6];
  const float* wo   = (const float*)d_in[7];
  const float* gam  = (const float*)d_in[8];
  const float* bet  = (const float*)d_in[9];
  float* out = (float*)d_out;

  char* w = (char*)d_ws;
  unsigned short* qkvo  = (unsigned short*)(w + 0);          // 50,331,648
  unsigned short* relo  = (unsigned short*)(w + 50331648);   // 16,777,216
  unsigned short* wo16  = (unsigned short*)(w + 67108864);   //  2,097,152
  unsigned short* QUb   = (unsigned short*)(w + 69206016);   //  8,388,608
  unsigned short* QVb   = (unsigned short*)(w + 77594624);   //  8,388,608
  unsigned short* VT    = (unsigned short*)(w + 85983232);   // 16,777,216
  unsigned short* av16  = (unsigned short*)(w + 102760448);  //  8,388,608
  float*          yf    = (float*)(w + 111149056);           // 16,777,216
  unsigned short* c16   = (unsigned short*)(w + 127926272);  // 16,777,216
  unsigned short* pos16 = (unsigned short*)(w + 144703488);  // 16,777,216
  unsigned short* wq16  = (unsigned short*)(w + 161480704);  //  6,291,456
  unsigned short* wr16  = (unsigned short*)(w + 167772160);  //  2,097,152 -> total 169,869,312

  cast_all<<<10752, 256, 0, stream>>>(mem, x, pos, wqkv, wrel, wo,
                                      c16, pos16, wq16, wr16, wo16);

  gemm_nt<<<dim3(24,64), 256, 0, stream>>>(c16,   wq16, (void*)qkvo, nullptr, 3072, 1024, 0);
  gemm_nt<<<dim3(8,64),  256, 0, stream>>>(pos16, wr16, (void*)relo, nullptr, 1024, 1024, 0);

  scatter_quv<<<2048, 256, 0, stream>>>(qkvo, pbu, pbv, QUb, QVb);
  scatter_vt<<<dim3(64,32), 256, 0, stream>>>(qkvo, VT);

  flash_attn4<<<dim3(64,16), 256, 0, stream>>>(QUb, QVb, qkvo, VT, relo, av16);

  gemm_nt<<<dim3(8,32), 256, 0, stream>>>(av16, wo16, (void*)yf, x, 1024, 1024, 1);
  ln_kernel<<<4096, 256, 0, stream>>>(yf, gam, bet, out);
}

// Round 10
// 466.504 us; speedup vs baseline: 1.0095x; 1.0095x over previous
//
#include <hip/hip_runtime.h>

#define S_ 1024
#define M_ 1024
#define T_ 2048
#define B_ 4
#define H_ 16
#define DM_ 1024
#define DH_ 64

typedef __attribute__((ext_vector_type(8))) short s16x8;
typedef __attribute__((ext_vector_type(16))) float f32x16;

__device__ __forceinline__ unsigned short f2b(float x){
  unsigned int u = __float_as_uint(x);
  u = (u + 0x7fffu + ((u>>16)&1u)) >> 16;
  return (unsigned short)u;
}
__device__ __forceinline__ float b2f(unsigned short h){
  return __uint_as_float(((unsigned int)h)<<16);
}
__device__ __forceinline__ uint4 pack8(const float* v){
  uint4 o;
  o.x = (unsigned)f2b(v[0]) | ((unsigned)f2b(v[1])<<16);
  o.y = (unsigned)f2b(v[2]) | ((unsigned)f2b(v[3])<<16);
  o.z = (unsigned)f2b(v[4]) | ((unsigned)f2b(v[5])<<16);
  o.w = (unsigned)f2b(v[6]) | ((unsigned)f2b(v[7])<<16);
  return o;
}
__device__ __forceinline__ void glds16(const unsigned short* g, unsigned short* l){
  __builtin_amdgcn_global_load_lds((const __attribute__((address_space(1))) void*)g,
                                   (__attribute__((address_space(3))) void*)l, 16, 0, 0);
}

// raw barriers:
//   BAR_L   waits only LDS ops (glds prefetches stay in flight)
//   BAR_VL  drains vmcnt fully
//   BAR_V6L counted drain: waits for the 2 OLDEST vmem ops (VT of this iter),
//           leaves the 6 newer K/R(j+1) prefetches in flight (T4).
#define BAR_L()   asm volatile("s_waitcnt lgkmcnt(0)\ns_barrier" ::: "memory")
#define BAR_VL()  asm volatile("s_waitcnt vmcnt(0) lgkmcnt(0)\ns_barrier" ::: "memory")
#define BAR_V6L() asm volatile("s_waitcnt vmcnt(6) lgkmcnt(0)\ns_barrier" ::: "memory")

// ---------------- fused cast kernel ----------------
__global__ __launch_bounds__(256) void cast_all(
    const float* __restrict__ mem, const float* __restrict__ x,
    const float* __restrict__ pos, const float* __restrict__ wqkv,
    const float* __restrict__ wrel, const float* __restrict__ wo,
    unsigned short* __restrict__ c16, unsigned short* __restrict__ pos16,
    unsigned short* __restrict__ wq16, unsigned short* __restrict__ wr16,
    unsigned short* __restrict__ wo16)
{
  int u = blockIdx.x*256 + threadIdx.x;
  const float* s; unsigned short* d;
  if (u < 1048576)      { s = (u < 524288) ? mem + (size_t)u*8 : x + (size_t)(u-524288)*8;
                          d = c16 + (size_t)u*8; }
  else if (u < 2097152) { int v = u - 1048576; s = pos  + (size_t)v*8; d = pos16 + (size_t)v*8; }
  else if (u < 2490368) { int v = u - 2097152; s = wqkv + (size_t)v*8; d = wq16  + (size_t)v*8; }
  else if (u < 2621440) { int v = u - 2490368; s = wrel + (size_t)v*8; d = wr16  + (size_t)v*8; }
  else                  { int v = u - 2621440; s = wo   + (size_t)v*8; d = wo16  + (size_t)v*8; }
  float4 x0 = *(const float4*)s;
  float4 x1 = *(const float4*)(s+4);
  float f[8] = {x0.x,x0.y,x0.z,x0.w,x1.x,x1.y,x1.z,x1.w};
  *(uint4*)d = pack8(f);
}

// ---------------- GEMM: C[M][N] = A[M][K] @ B[N][K]^T  (bf16 in, NT) ----------------
__global__ __launch_bounds__(256) void gemm_nt(const unsigned short* __restrict__ A,
    const unsigned short* __restrict__ Bw, void* __restrict__ Cout,
    const float* __restrict__ res, int Ntot, int K, int mode)
{
  __shared__ __align__(16) unsigned short a_s[128*64];
  __shared__ __align__(16) unsigned short b_s[128*64];
  const int tid = threadIdx.x;
  const int lane = tid & 63, wave = tid >> 6;
  const int wr = wave >> 1, wc = wave & 1;
  const long m0 = (long)blockIdx.y * 128, n0 = (long)blockIdx.x * 128;
  f32x16 acc[2][2];
  for (int qa=0;qa<2;qa++) for(int qb=0;qb<2;qb++) for (int e=0;e<16;e++) acc[qa][qb][e]=0.f;
  int srow[4], scol[4];
  for (int c = 0; c < 4; c++) {
    int ch = c*256 + tid;
    srow[c] = ch >> 3;
    scol[c] = (((ch & 7) ^ (srow[c] & 7))) * 8;
  }
  for (int k0 = 0; k0 < K; k0 += 64) {
    for (int c = 0; c < 4; c++) {
      int ch = c*256 + tid;
      glds16(&A[(size_t)(m0+srow[c])*K + k0 + scol[c]], &a_s[ch*8]);
      glds16(&Bw[(size_t)(n0+srow[c])*K + k0 + scol[c]], &b_s[ch*8]);
    }
    __syncthreads();
    for (int ks = 0; ks < 4; ks++) {
      const int kb = ks*2 + (lane>>5);
      s16x8 af[2], bf[2];
      for (int q = 0; q < 2; q++) {
        int ra = wr*64 + q*32 + (lane&31);
        int rb = wc*64 + q*32 + (lane&31);
        af[q] = *(const s16x8*)&a_s[ra*64 + ((kb ^ (ra&7))<<3)];
        bf[q] = *(const s16x8*)&b_s[rb*64 + ((kb ^ (rb&7))<<3)];
      }
      for (int qr=0;qr<2;qr++)
        for (int qc2=0;qc2<2;qc2++)
          acc[qr][qc2] = __builtin_amdgcn_mfma_f32_32x32x16_bf16(af[qr], bf[qc2], acc[qr][qc2], 0,0,0);
    }
    __syncthreads();
  }
  for (int qr=0;qr<2;qr++)
    for (int qc2=0;qc2<2;qc2++)
      for (int e=0;e<16;e++){
        long row = m0 + wr*64 + qr*32 + (e&3) + 8*(e>>2) + 4*(lane>>5);
        long col = n0 + wc*64 + qc2*32 + (lane&31);
        size_t o = (size_t)row*Ntot + col;
        if (mode == 0) ((unsigned short*)Cout)[o] = f2b(acc[qr][qc2][e]);
        else           ((float*)Cout)[o] = acc[qr][qc2][e] + res[o];
      }
}

// ---------------- fused scatter: quv (blocks 0..2047) + vt (blocks 2048..4095) ----------------
__global__ __launch_bounds__(256) void scatter_all(const unsigned short* __restrict__ qkvo,
   const float* __restrict__ u, const float* __restrict__ v,
   unsigned short* __restrict__ QU, unsigned short* __restrict__ QV,
   unsigned short* __restrict__ VT)
{
  __shared__ __align__(16) unsigned short v_s[64*72];
  const int tid = threadIdx.x;
  if (blockIdx.x < 2048) {
    // scatter_quv: q + biases, per-head layout
    int gid = blockIdx.x*256 + tid;   // B*H*S*8 = 524288
    int d0 = (gid & 7) * 8;
    int i  = (gid >> 3) & (S_-1);
    int bh = gid >> 13;
    int b = bh >> 4, h = bh & 15;
    size_t src = (size_t)((M_+i)*B_ + b)*3072 + h*64 + d0;
    uint4 q8 = *(const uint4*)&qkvo[src];
    float f[8];
    f[0]=b2f(q8.x&0xffff); f[1]=b2f(q8.x>>16); f[2]=b2f(q8.y&0xffff); f[3]=b2f(q8.y>>16);
    f[4]=b2f(q8.z&0xffff); f[5]=b2f(q8.z>>16); f[6]=b2f(q8.w&0xffff); f[7]=b2f(q8.w>>16);
    float fu[8], fv[8];
    for (int e=0;e<8;e++){ fu[e] = f[e] + u[h*64+d0+e]; fv[e] = f[e] + v[h*64+d0+e]; }
    size_t dst = ((size_t)bh*S_ + i)*64 + d0;
    *(uint4*)&QU[dst] = pack8(fu);
    *(uint4*)&QV[dst] = pack8(fv);
  } else {
    // scatter_vt: VT[bh][d][t] = V[t][b][h][d] (LDS transpose)
    const int idx = blockIdx.x - 2048;
    const int bh = idx & 63, b = bh>>4, h = bh&15;
    const int t0 = (idx >> 6) * 64;
    const unsigned short* Vg = qkvo + (size_t)b*3072 + 2048 + h*64;
    for (int c=0;c<2;c++){
      int ch = c*256 + tid;
      int r = ch>>3, off = (ch&7)*8;
      *(uint4*)&v_s[r*72+off] = *(const uint4*)&Vg[(size_t)(t0+r)*12288 + off];
    }
    __syncthreads();
    for (int c=0;c<2;c++){
      int ch = c*256 + tid;
      int d = ch>>3, toff = (ch&7)*8;
      unsigned short vals[8];
      for (int e=0;e<8;e++) vals[e] = v_s[(toff+e)*72 + d];
      uint4 pk;
      pk.x = (unsigned)vals[0] | ((unsigned)vals[1]<<16);
      pk.y = (unsigned)vals[2] | ((unsigned)vals[3]<<16);
      pk.z = (unsigned)vals[4] | ((unsigned)vals[5]<<16);
      pk.w = (unsigned)vals[6] | ((unsigned)vals[7]<<16);
      *(uint4*)&VT[((size_t)bh*64 + d)*T_ + t0 + toff] = pk;
    }
  }
}

// ---------------- fused attention v13 (unchanged from round 9; verified 194 µs) ----------------
__global__ __launch_bounds__(256,2) void flash_attn4(
    const unsigned short* __restrict__ QU, const unsigned short* __restrict__ QV,
    const unsigned short* __restrict__ qkvo, const unsigned short* __restrict__ VT,
    const unsigned short* __restrict__ relo, unsigned short* __restrict__ AV)
{
  __shared__ __align__(16) unsigned short qv_s[65*72];
  __shared__ __align__(16) unsigned short k_s [2][64*64];   // XOR-64, double-buffered
  __shared__ __align__(16) unsigned short vt_s[64*64];      // XOR-64, single buffer
  __shared__ __align__(16) unsigned short rg_s[2][128*64];  // R window, double-buffered
  __shared__ __align__(16) unsigned short p_s [64*64];      // QU staging, then P (XOR-64)
  __shared__ float l_s[64];

  const int tid = threadIdx.x, lane = tid&63, wave = tid>>6;
  const int bh = blockIdx.x, b = bh>>4, h = bh&15;
  const int i0 = blockIdx.y*64;
  const int qr = wave>>1, qc = wave&1;
  const int hi = lane>>5, ll = lane&31;
  const unsigned short* QUb = QU + (size_t)bh*S_*DH_;
  const unsigned short* QVb = QV + (size_t)bh*S_*DH_;
  const unsigned short* Kg  = qkvo + (size_t)b*3072 + 1024 + h*64;   // + t*12288
  const unsigned short* VTb = VT + (size_t)bh*64*T_;
  const unsigned short* Rg  = relo + (size_t)b*1024 + h*64;          // + t*4096

  // per-thread staging geometry (2-chunk tiles: K, VT)
  const int s0r = tid>>3,        s0c = (((tid&7)       ^ (s0r&7)))*8;
  const int s1r = (256+tid)>>3,  s1c = ((((256+tid)&7) ^ (s1r&7)))*8;

  // ---- prologue: DMA K(0)->k_s[0], R(0)->rg_s[0]; stage QU->p_s, QV->qv_s ----
  glds16(&Kg [(size_t)(0+s0r)*12288 + s0c], &k_s[0][(size_t)tid*8]);
  glds16(&Kg [(size_t)(0+s1r)*12288 + s1c], &k_s[0][(size_t)(256+tid)*8]);
  {
    const int wb0 = 0 - i0 + 960;    // j0=0 is always cls 0
    for (int c=0;c<4;c++){
      int ch = c*256+tid; int rr = ch>>3, off = ch&7;
      int t = wb0 + rr; t = t < 0 ? 0 : (t > T_-1 ? T_-1 : t);
      glds16(&Rg[(size_t)t*4096 + ((off ^ (rr&7)))*8], &rg_s[0][(size_t)ch*8]);
    }
  }
  for (int c=0;c<2;c++){
    int ch = c*256+tid; int row = ch>>3, off=(ch&7);
    *(uint4*)&p_s[row*64 + ((off ^ (row&7))<<3)] = *(const uint4*)&QUb[(size_t)(i0+row)*64 + off*8];
    *(uint4*)&qv_s[row*72+off*8] = *(const uint4*)&QVb[(size_t)(i0+row)*64 + off*8];
  }
  if (tid < 8) {
    int rr = i0 + 64; if (rr > S_-1) rr = S_-1;
    *(uint4*)&qv_s[64*72 + tid*8] = *(const uint4*)&QVb[(size_t)rr*64 + tid*8];
  }
  BAR_L();   // QU/QV plain stores visible

  // ---- Q-hoist: j-invariant A-fragments into registers (32 VGPRs) ----
  s16x8 qur0, qur1, qur2, qur3;     // QU row qr*32+ll (from p_s XOR-64)
  s16x8 qv00, qv01, qv02, qv03;     // QV row qr*32+ll (shift 0)
  {
    const int rq = qr*32 + ll;
    qur0 = *(const s16x8*)&p_s[rq*64 + (((0*2+hi) ^ (rq&7))<<3)];
    qur1 = *(const s16x8*)&p_s[rq*64 + (((1*2+hi) ^ (rq&7))<<3)];
    qur2 = *(const s16x8*)&p_s[rq*64 + (((2*2+hi) ^ (rq&7))<<3)];
    qur3 = *(const s16x8*)&p_s[rq*64 + (((3*2+hi) ^ (rq&7))<<3)];
    const int ro = rq*72 + hi*8;
    qv00 = *(const s16x8*)&qv_s[ro +  0];
    qv01 = *(const s16x8*)&qv_s[ro + 16];
    qv02 = *(const s16x8*)&qv_s[ro + 32];
    qv03 = *(const s16x8*)&qv_s[ro + 48];
  }
  // (no barrier here: the first loop-top BAR_VL drains K/R(0) vmem and each
  //  wave's hoist lgkm reads before gather(0) can overwrite p_s)

  s16x8 ones;
  for (int e=0;e<8;e++) ones[e] = (short)0x3F80;   // bf16 1.0

  f32x16 acc_o, acc_l;
  for (int e=0;e<16;e++){ acc_o[e]=0.f; acc_l[e]=0.f; }

  const int col = qc*32 + ll;
  const int cbase = (qc - qr + 1) * 32;   // wave's band-quad column base

  int cur = 0;
  for (int j0 = 0; j0 < T_; j0 += 64) {
    const int jdmax = j0 + 63 - i0;
    const int jdmin = j0 - 63 - i0;
    const int cls = (jdmax <= 1024) ? 0 : ((jdmin >= 1026) ? 2 : 1);
    const int jn = j0 + 64;
    unsigned short* kc = &k_s[cur][0];
    unsigned short* rc = &rg_s[cur][0];
    unsigned short* kn = &k_s[cur^1][0];
    unsigned short* rn = &rg_s[cur^1][0];

    BAR_VL();                  // B1: PV(j-1)/hoist lgkm done; K(j)/R(j) landed

    // stage VT(j) FIRST (oldest vmem pair -> B3's counted drain targets it)
    glds16(&VTb[(size_t)s0r*T_ + j0 + s0c], &vt_s[(size_t)tid*8]);
    glds16(&VTb[(size_t)s1r*T_ + j0 + s1c], &vt_s[(size_t)(256+tid)*8]);
    // prefetch K/R(j+1) into the other buffers (no WAR: reads use buf[cur])
    if (jn < T_) {
      glds16(&Kg[(size_t)(jn+s0r)*12288 + s0c], &kn[(size_t)tid*8]);
      glds16(&Kg[(size_t)(jn+s1r)*12288 + s1c], &kn[(size_t)(256+tid)*8]);
      const int jdmaxn = jn + 63 - i0;
      const int jdminn = jn - 63 - i0;
      const int clsn = (jdmaxn <= 1024) ? 0 : ((jdminn >= 1026) ? 2 : 1);
      const int wbn = (clsn == 2) ? (jn - i0 - 1089) : (jn - i0 + 960);
      for (int c=0;c<4;c++){
        int ch = c*256+tid; int rr = ch>>3, off = ch&7;
        int t = wbn + rr; t = t < 0 ? 0 : (t > T_-1 ? T_-1 : t);
        glds16(&Rg[(size_t)t*4096 + ((off ^ (rr&7)))*8], &rn[(size_t)ch*8]);
      }
    }

    // band A-operand: hoisted shift-0 regs, or LDS shift-1 rows for cls2
    s16x8 av0, av1, av2, av3;
    if (cls == 2) {
      const int ro1 = (qr*32+ll+1)*72 + hi*8;
      av0 = *(const s16x8*)&qv_s[ro1 +  0];
      av1 = *(const s16x8*)&qv_s[ro1 + 16];
      av2 = *(const s16x8*)&qv_s[ro1 + 32];
      av3 = *(const s16x8*)&qv_s[ro1 + 48];
    } else {
      av0 = qv00; av1 = qv01; av2 = qv02; av3 = qv03;
    }

    // band GEMM: the wave's OWN 2 quads at cbase (kept in registers)
    f32x16 gacc0, gacc1;
    for (int e=0;e<16;e++){ gacc0[e]=0.f; gacc1[e]=0.f; }
    __builtin_amdgcn_s_setprio(1);
#define BANDK(KS, AV) { \
      int kb = KS*2 + hi; \
      { int br = cbase + ll; \
        s16x8 bb = *(const s16x8*)&rc[br*64 + ((kb ^ (br&7))<<3)]; \
        gacc0 = __builtin_amdgcn_mfma_f32_32x32x16_bf16(AV, bb, gacc0, 0,0,0); } \
      { int br = cbase + 32 + ll; \
        s16x8 bb = *(const s16x8*)&rc[br*64 + ((kb ^ (br&7))<<3)]; \
        gacc1 = __builtin_amdgcn_mfma_f32_32x32x16_bf16(AV, bb, gacc1, 0,0,0); } }
    BANDK(0, av0) BANDK(1, av1) BANDK(2, av2) BANDK(3, av3)

    // AC quad (hoisted qur, kc in XOR-64 layout)
    f32x16 acc;
    for (int e=0;e<16;e++) acc[e]=0.f;
#define ACK(KS, AU) { \
      int kb = KS*2 + hi; \
      int rbk = qc*32 + ll; \
      s16x8 bq = *(const s16x8*)&kc[rbk*64 + ((kb ^ (rbk&7))<<3)]; \
      acc = __builtin_amdgcn_mfma_f32_32x32x16_bf16(AU, bq, acc, 0,0,0); }
    ACK(0, qur0) ACK(1, qur1) ACK(2, qur2) ACK(3, qur3)
    __builtin_amdgcn_s_setprio(0);

    // in-register gather (select-then-permute, 16 bperm) + exp -> P (XOR-64)
    for (int e=0;e<16;e++){
      int rm = 4*hi + (e&3) + 8*(e>>2);     // r - qr*32
      int r  = qr*32 + rm;
      int jd = j0 + col - (i0 + r);
      int tl = (ll + rm + 1) & 31;          // target lane fed by this source
      float sel = (tl > rm) ? gacc1[e] : gacc0[e];
      int li = ((((ll - rm + 31) & 31) | (hi<<5)) << 2);
      float bd = __uint_as_float((unsigned)__builtin_amdgcn_ds_bpermute(li, (int)__float_as_uint(sel)));
      if (jd == 1025) bd = 0.f;
      float p = __expf((acc[e] + bd) * 0.125f);
      if (!(cls == 1 && jd >= 1026))
        p_s[r*64 + (((col>>3) ^ (r&7))<<3) + (col&7)] = f2b(p);
    }

    if (cls == 1) {
      BAR_L();                 // C1: all waves' band reads of rc done
      // stage wrap R window into rc (dead after band)
      const int wb2 = j0 - i0 - 1089;
      for (int c=0;c<4;c++){
        int ch = c*256+tid; int rr = ch>>3, off = ch&7;
        int t = wb2 + rr; t = t < 0 ? 0 : (t > T_-1 ? T_-1 : t);
        glds16(&Rg[(size_t)t*4096 + ((off ^ (rr&7)))*8], &rc[(size_t)ch*8]);
      }
      BAR_VL();                // C2: wrap R landed (drains VT/K/R(j+1) too; 1x per block)
      f32x16 g2a, g2b;
      for (int e=0;e<16;e++){ g2a[e]=0.f; g2b[e]=0.f; }
      __builtin_amdgcn_s_setprio(1);
#define BANDW(KS) { \
        int kb = KS*2 + hi; \
        const int ro1 = (qr*32+ll+1)*72 + hi*8; \
        s16x8 a = *(const s16x8*)&qv_s[ro1 + KS*16]; \
        { int br = cbase + ll; \
          s16x8 bb = *(const s16x8*)&rc[br*64 + ((kb ^ (br&7))<<3)]; \
          g2a = __builtin_amdgcn_mfma_f32_32x32x16_bf16(a, bb, g2a, 0,0,0); } \
        { int br = cbase + 32 + ll; \
          s16x8 bb = *(const s16x8*)&rc[br*64 + ((kb ^ (br&7))<<3)]; \
          g2b = __builtin_amdgcn_mfma_f32_32x32x16_bf16(a, bb, g2b, 0,0,0); } }
      BANDW(0) BANDW(1) BANDW(2) BANDW(3)
      __builtin_amdgcn_s_setprio(0);
      for (int e=0;e<16;e++){
        int rm = 4*hi + (e&3) + 8*(e>>2);
        int r  = qr*32 + rm;
        int jd = j0 + col - (i0 + r);
        int tl = (ll + rm + 1) & 31;
        float sel = (tl > rm) ? g2b[e] : g2a[e];
        int li = ((((ll - rm + 31) & 31) | (hi<<5)) << 2);
        float bd = __uint_as_float((unsigned)__builtin_amdgcn_ds_bpermute(li, (int)__float_as_uint(sel)));
        float p = __expf((acc[e] + bd) * 0.125f);
        if (jd >= 1026)
          p_s[r*64 + (((col>>3) ^ (r&7))<<3) + (col&7)] = f2b(p);
      }
    }

    // B3: P visible; VT(j) landed (counted: K/R(j+1) stay in flight).
    // cls1 already fully drained at C2 -> vmcnt(6) is a no-op there.
    if (jn < T_) { BAR_V6L(); } else { BAR_VL(); }

    // PV quad + MFMA rowsum (A-fragments from p_s XOR-64)
    __builtin_amdgcn_s_setprio(1);
    for (int ks=0; ks<4; ks++){
      int kb = ks*2 + hi;
      int rv = qr*32 + ll, rbv = qc*32 + ll;
      s16x8 a  = *(const s16x8*)&p_s[rv*64 + ((kb ^ (rv&7))<<3)];
      s16x8 bv = *(const s16x8*)&vt_s[rbv*64 + ((kb ^ (rbv&7))<<3)];
      acc_o = __builtin_amdgcn_mfma_f32_32x32x16_bf16(a, bv, acc_o, 0,0,0);
      acc_l = __builtin_amdgcn_mfma_f32_32x32x16_bf16(a, ones, acc_l, 0,0,0);
    }
    __builtin_amdgcn_s_setprio(0);
    cur ^= 1;
    // no trailing barrier: loop-top B1 orders everything
  }

  // epilogue: l from acc_l (every lane's acc_l[e] = rowsum of row r)
  if (qc == 0 && ll == 0) {
    for (int e=0;e<16;e++){
      int r = qr*32 + 4*hi + (e&3) + 8*(e>>2);
      l_s[r] = acc_l[e];
    }
  }
  BAR_L();
  for (int e=0;e<16;e++){
    int r = qr*32 + 4*hi + (e&3) + 8*(e>>2);
    float oo = acc_o[e] / l_s[r];
    AV[ ((size_t)(i0+r)*B_ + b)*(H_*DH_) + h*DH_ + col ] = f2b(oo);
  }
#undef BANDK
#undef ACK
#undef BANDW
}

// ---------------- LayerNorm ----------------
__global__ __launch_bounds__(256) void ln_kernel(const float* __restrict__ y,
    const float* __restrict__ g, const float* __restrict__ be, float* __restrict__ o)
{
  __shared__ float red[8];
  int row = blockIdx.x, tid = threadIdx.x;
  const float* yr = y + (size_t)row*DM_;
  float v[4];
  for (int e=0;e<4;e++) v[e] = yr[tid + 256*e];
  float s = v[0]+v[1]+v[2]+v[3];
  for (int off=32; off>0; off>>=1) s += __shfl_down(s, off, 64);
  if ((tid&63)==0) red[tid>>6] = s;
  __syncthreads();
  if (tid==0) red[4] = red[0]+red[1]+red[2]+red[3];
  __syncthreads();
  float mu = red[4] * (1.f/DM_);
  __syncthreads();
  float q = 0.f;
  for (int e=0;e<4;e++){ float d = v[e]-mu; q += d*d; }
  for (int off=32; off>0; off>>=1) q += __shfl_down(q, off, 64);
  if ((tid&63)==0) red[tid>>6] = q;
  __syncthreads();
  if (tid==0) red[4] = red[0]+red[1]+red[2]+red[3];
  __syncthreads();
  float rstd = rsqrtf(red[4]*(1.f/DM_) + 1e-5f);
  for (int e=0;e<4;e++){
    int c = tid + 256*e;
    o[(size_t)row*DM_ + c] = g[c]*(v[e]-mu)*rstd + be[c];
  }
}

// ---------------- launch ----------------
extern "C" void kernel_launch(void* const* d_in, const int* in_sizes, int n_in,
                              void* d_out, int out_size, void* d_ws, size_t ws_size,
                              hipStream_t stream)
{
  const float* x    = (const float*)d_in[0];
  const float* mem  = (const float*)d_in[1];
  const float* pos  = (const float*)d_in[2];
  const float* pbu  = (const float*)d_in[3];
  const float* pbv  = (const float*)d_in[4];
  const float* wqkv = (const float*)d_in[5];
  const float* wrel = (const float*)d_in[6];
  const float* wo   = (const float*)d_in[7];
  const float* gam  = (const float*)d_in[8];
  const float* bet  = (const float*)d_in[9];
  float* out = (float*)d_out;

  char* w = (char*)d_ws;
  unsigned short* qkvo  = (unsigned short*)(w + 0);          // 50,331,648
  unsigned short* relo  = (unsigned short*)(w + 50331648);   // 16,777,216
  unsigned short* wo16  = (unsigned short*)(w + 67108864);   //  2,097,152
  unsigned short* QUb   = (unsigned short*)(w + 69206016);   //  8,388,608
  unsigned short* QVb   = (unsigned short*)(w + 77594624);   //  8,388,608
  unsigned short* VT    = (unsigned short*)(w + 85983232);   // 16,777,216
  unsigned short* av16  = (unsigned short*)(w + 102760448);  //  8,388,608
  float*          yf    = (float*)(w + 111149056);           // 16,777,216
  unsigned short* c16   = (unsigned short*)(w + 127926272);  // 16,777,216
  unsigned short* pos16 = (unsigned short*)(w + 144703488);  // 16,777,216
  unsigned short* wq16  = (unsigned short*)(w + 161480704);  //  6,291,456
  unsigned short* wr16  = (unsigned short*)(w + 167772160);  //  2,097,152 -> total 169,869,312

  cast_all<<<10752, 256, 0, stream>>>(mem, x, pos, wqkv, wrel, wo,
                                      c16, pos16, wq16, wr16, wo16);

  // QKV split: KV for ALL T rows (cols 1024..3072), Q only for the x rows
  // (rows 4096..8192 of c16, cols 0..1024). Q for mem rows is never read
  // (scatter reads rows (M+i)*B+b only) -> skip computing it: -8.6 GFLOP.
  gemm_nt<<<dim3(16,64), 256, 0, stream>>>(c16, wq16 + (size_t)1024*1024,
                                           (void*)(qkvo + 1024), nullptr, 3072, 1024, 0);
  gemm_nt<<<dim3(8,32),  256, 0, stream>>>(c16 + (size_t)4096*1024, wq16,
                                           (void*)(qkvo + (size_t)4096*3072), nullptr, 3072, 1024, 0);
  gemm_nt<<<dim3(8,64),  256, 0, stream>>>(pos16, wr16, (void*)relo, nullptr, 1024, 1024, 0);

  scatter_all<<<4096, 256, 0, stream>>>(qkvo, pbu, pbv, QUb, QVb, VT);

  flash_attn4<<<dim3(64,16), 256, 0, stream>>>(QUb, QVb, qkvo, VT, relo, av16);

  gemm_nt<<<dim3(8,32), 256, 0, stream>>>(av16, wo16, (void*)yf, x, 1024, 1024, 1);
  ln_kernel<<<4096, 256, 0, stream>>>(yf, gam, bet, out);
}

// Round 11
// 455.539 us; speedup vs baseline: 1.0338x; 1.0241x over previous
//
#include <hip/hip_runtime.h>

#define S_ 1024
#define M_ 1024
#define T_ 2048
#define B_ 4
#define H_ 16
#define DM_ 1024
#define DH_ 64

typedef __attribute__((ext_vector_type(8))) short s16x8;
typedef __attribute__((ext_vector_type(16))) float f32x16;

__device__ __forceinline__ unsigned short f2b(float x){
  unsigned int u = __float_as_uint(x);
  u = (u + 0x7fffu + ((u>>16)&1u)) >> 16;
  return (unsigned short)u;
}
__device__ __forceinline__ float b2f(unsigned short h){
  return __uint_as_float(((unsigned int)h)<<16);
}
__device__ __forceinline__ uint4 pack8(const float* v){
  uint4 o;
  o.x = (unsigned)f2b(v[0]) | ((unsigned)f2b(v[1])<<16);
  o.y = (unsigned)f2b(v[2]) | ((unsigned)f2b(v[3])<<16);
  o.z = (unsigned)f2b(v[4]) | ((unsigned)f2b(v[5])<<16);
  o.w = (unsigned)f2b(v[6]) | ((unsigned)f2b(v[7])<<16);
  return o;
}
__device__ __forceinline__ void glds16(const unsigned short* g, unsigned short* l){
  __builtin_amdgcn_global_load_lds((const __attribute__((address_space(1))) void*)g,
                                   (__attribute__((address_space(3))) void*)l, 16, 0, 0);
}

// raw barriers:
//   BAR_L   waits only LDS ops (glds prefetches stay in flight)
//   BAR_VL  drains vmcnt fully
//   BAR_V6L counted drain: waits for the 2 OLDEST vmem ops (VT of this iter),
//           leaves the 6 newer K/R(j+1) prefetches in flight (T4).
#define BAR_L()   asm volatile("s_waitcnt lgkmcnt(0)\ns_barrier" ::: "memory")
#define BAR_VL()  asm volatile("s_waitcnt vmcnt(0) lgkmcnt(0)\ns_barrier" ::: "memory")
#define BAR_V6L() asm volatile("s_waitcnt vmcnt(6) lgkmcnt(0)\ns_barrier" ::: "memory")

// ---------------- fused cast kernel ----------------
__global__ __launch_bounds__(256) void cast_all(
    const float* __restrict__ mem, const float* __restrict__ x,
    const float* __restrict__ pos, const float* __restrict__ wqkv,
    const float* __restrict__ wrel, const float* __restrict__ wo,
    unsigned short* __restrict__ c16, unsigned short* __restrict__ pos16,
    unsigned short* __restrict__ wq16, unsigned short* __restrict__ wr16,
    unsigned short* __restrict__ wo16)
{
  int u = blockIdx.x*256 + threadIdx.x;
  const float* s; unsigned short* d;
  if (u < 1048576)      { s = (u < 524288) ? mem + (size_t)u*8 : x + (size_t)(u-524288)*8;
                          d = c16 + (size_t)u*8; }
  else if (u < 2097152) { int v = u - 1048576; s = pos  + (size_t)v*8; d = pos16 + (size_t)v*8; }
  else if (u < 2490368) { int v = u - 2097152; s = wqkv + (size_t)v*8; d = wq16  + (size_t)v*8; }
  else if (u < 2621440) { int v = u - 2490368; s = wrel + (size_t)v*8; d = wr16  + (size_t)v*8; }
  else                  { int v = u - 2621440; s = wo   + (size_t)v*8; d = wo16  + (size_t)v*8; }
  float4 x0 = *(const float4*)s;
  float4 x1 = *(const float4*)(s+4);
  float f[8] = {x0.x,x0.y,x0.z,x0.w,x1.x,x1.y,x1.z,x1.w};
  *(uint4*)d = pack8(f);
}

// ---------------- GEMM: C[M][N] = A[M][K] @ B[N][K]^T  (bf16 in, NT) ----------------
__global__ __launch_bounds__(256) void gemm_nt(const unsigned short* __restrict__ A,
    const unsigned short* __restrict__ Bw, void* __restrict__ Cout,
    const float* __restrict__ res, int Ntot, int K, int mode)
{
  __shared__ __align__(16) unsigned short a_s[128*64];
  __shared__ __align__(16) unsigned short b_s[128*64];
  const int tid = threadIdx.x;
  const int lane = tid & 63, wave = tid >> 6;
  const int wr = wave >> 1, wc = wave & 1;
  const long m0 = (long)blockIdx.y * 128, n0 = (long)blockIdx.x * 128;
  f32x16 acc[2][2];
  for (int qa=0;qa<2;qa++) for(int qb=0;qb<2;qb++) for (int e=0;e<16;e++) acc[qa][qb][e]=0.f;
  int srow[4], scol[4];
  for (int c = 0; c < 4; c++) {
    int ch = c*256 + tid;
    srow[c] = ch >> 3;
    scol[c] = (((ch & 7) ^ (srow[c] & 7))) * 8;
  }
  for (int k0 = 0; k0 < K; k0 += 64) {
    for (int c = 0; c < 4; c++) {
      int ch = c*256 + tid;
      glds16(&A[(size_t)(m0+srow[c])*K + k0 + scol[c]], &a_s[ch*8]);
      glds16(&Bw[(size_t)(n0+srow[c])*K + k0 + scol[c]], &b_s[ch*8]);
    }
    __syncthreads();
    for (int ks = 0; ks < 4; ks++) {
      const int kb = ks*2 + (lane>>5);
      s16x8 af[2], bf[2];
      for (int q = 0; q < 2; q++) {
        int ra = wr*64 + q*32 + (lane&31);
        int rb = wc*64 + q*32 + (lane&31);
        af[q] = *(const s16x8*)&a_s[ra*64 + ((kb ^ (ra&7))<<3)];
        bf[q] = *(const s16x8*)&b_s[rb*64 + ((kb ^ (rb&7))<<3)];
      }
      for (int qr=0;qr<2;qr++)
        for (int qc2=0;qc2<2;qc2++)
          acc[qr][qc2] = __builtin_amdgcn_mfma_f32_32x32x16_bf16(af[qr], bf[qc2], acc[qr][qc2], 0,0,0);
    }
    __syncthreads();
  }
  for (int qr=0;qr<2;qr++)
    for (int qc2=0;qc2<2;qc2++)
      for (int e=0;e<16;e++){
        long row = m0 + wr*64 + qr*32 + (e&3) + 8*(e>>2) + 4*(lane>>5);
        long col = n0 + wc*64 + qc2*32 + (lane&31);
        size_t o = (size_t)row*Ntot + col;
        if (mode == 0) ((unsigned short*)Cout)[o] = f2b(acc[qr][qc2][e]);
        else           ((float*)Cout)[o] = acc[qr][qc2][e] + res[o];
      }
}

// ---------------- V-GEMM writing V^T directly ----------------
// C[i=h*64+d][t] = Wv[i] . c16[t*4+b],  b = blockIdx.z
// VT[(b*16+h)*64+d][t] = C[i][t]  -> o = b*2097152 + i*2048 + t (contiguous in t).
__global__ __launch_bounds__(256) void gemm_vt(const unsigned short* __restrict__ A,
    const unsigned short* __restrict__ Bw, unsigned short* __restrict__ VT)
{
  __shared__ __align__(16) unsigned short a_s[128*64];
  __shared__ __align__(16) unsigned short b_s[128*64];
  const int tid = threadIdx.x;
  const int lane = tid & 63, wave = tid >> 6;
  const int wr = wave >> 1, wc = wave & 1;
  const int bz = blockIdx.z;
  const long m0 = (long)blockIdx.y * 128, n0 = (long)blockIdx.x * 128;
  f32x16 acc[2][2];
  for (int qa=0;qa<2;qa++) for(int qb=0;qb<2;qb++) for (int e=0;e<16;e++) acc[qa][qb][e]=0.f;
  int srow[4], scol[4];
  for (int c = 0; c < 4; c++) {
    int ch = c*256 + tid;
    srow[c] = ch >> 3;
    scol[c] = (((ch & 7) ^ (srow[c] & 7))) * 8;
  }
  for (int k0 = 0; k0 < 1024; k0 += 64) {
    for (int c = 0; c < 4; c++) {
      int ch = c*256 + tid;
      glds16(&A[(size_t)(m0+srow[c])*1024 + k0 + scol[c]], &a_s[ch*8]);
      glds16(&Bw[((size_t)(n0+srow[c])*4 + bz)*1024 + k0 + scol[c]], &b_s[ch*8]);
    }
    __syncthreads();
    for (int ks = 0; ks < 4; ks++) {
      const int kb = ks*2 + (lane>>5);
      s16x8 af[2], bf[2];
      for (int q = 0; q < 2; q++) {
        int ra = wr*64 + q*32 + (lane&31);
        int rb = wc*64 + q*32 + (lane&31);
        af[q] = *(const s16x8*)&a_s[ra*64 + ((kb ^ (ra&7))<<3)];
        bf[q] = *(const s16x8*)&b_s[rb*64 + ((kb ^ (rb&7))<<3)];
      }
      for (int qr=0;qr<2;qr++)
        for (int qc2=0;qc2<2;qc2++)
          acc[qr][qc2] = __builtin_amdgcn_mfma_f32_32x32x16_bf16(af[qr], bf[qc2], acc[qr][qc2], 0,0,0);
    }
    __syncthreads();
  }
  for (int qr=0;qr<2;qr++)
    for (int qc2=0;qc2<2;qc2++)
      for (int e=0;e<16;e++){
        long row = m0 + wr*64 + qr*32 + (e&3) + 8*(e>>2) + 4*(lane>>5);
        long col = n0 + wc*64 + qc2*32 + (lane&31);
        VT[(size_t)bz*2097152 + (size_t)row*2048 + col] = f2b(acc[qr][qc2][e]);
      }
}

// ---------------- Q-GEMM with fused u/v bias -> QU/QV per-head layout ----------------
// A = c16 rows 4096..8191 (row = i*4+b), Bw = Wq (rows 0..1024).
// dst = ((b*16+h)*1024 + i)*64 + d,  h=col>>6, d=col&63.
__global__ __launch_bounds__(256) void gemm_q(const unsigned short* __restrict__ A,
    const unsigned short* __restrict__ Bw, const float* __restrict__ u,
    const float* __restrict__ v, unsigned short* __restrict__ QU,
    unsigned short* __restrict__ QV)
{
  __shared__ __align__(16) unsigned short a_s[128*64];
  __shared__ __align__(16) unsigned short b_s[128*64];
  const int tid = threadIdx.x;
  const int lane = tid & 63, wave = tid >> 6;
  const int wr = wave >> 1, wc = wave & 1;
  const long m0 = (long)blockIdx.y * 128, n0 = (long)blockIdx.x * 128;
  f32x16 acc[2][2];
  for (int qa=0;qa<2;qa++) for(int qb=0;qb<2;qb++) for (int e=0;e<16;e++) acc[qa][qb][e]=0.f;
  int srow[4], scol[4];
  for (int c = 0; c < 4; c++) {
    int ch = c*256 + tid;
    srow[c] = ch >> 3;
    scol[c] = (((ch & 7) ^ (srow[c] & 7))) * 8;
  }
  for (int k0 = 0; k0 < 1024; k0 += 64) {
    for (int c = 0; c < 4; c++) {
      int ch = c*256 + tid;
      glds16(&A[(size_t)(m0+srow[c])*1024 + k0 + scol[c]], &a_s[ch*8]);
      glds16(&Bw[(size_t)(n0+srow[c])*1024 + k0 + scol[c]], &b_s[ch*8]);
    }
    __syncthreads();
    for (int ks = 0; ks < 4; ks++) {
      const int kb = ks*2 + (lane>>5);
      s16x8 af[2], bf[2];
      for (int q = 0; q < 2; q++) {
        int ra = wr*64 + q*32 + (lane&31);
        int rb = wc*64 + q*32 + (lane&31);
        af[q] = *(const s16x8*)&a_s[ra*64 + ((kb ^ (ra&7))<<3)];
        bf[q] = *(const s16x8*)&b_s[rb*64 + ((kb ^ (rb&7))<<3)];
      }
      for (int qr=0;qr<2;qr++)
        for (int qc2=0;qc2<2;qc2++)
          acc[qr][qc2] = __builtin_amdgcn_mfma_f32_32x32x16_bf16(af[qr], bf[qc2], acc[qr][qc2], 0,0,0);
    }
    __syncthreads();
  }
  for (int qr=0;qr<2;qr++)
    for (int qc2=0;qc2<2;qc2++)
      for (int e=0;e<16;e++){
        long row = m0 + wr*64 + qr*32 + (e&3) + 8*(e>>2) + 4*(lane>>5);  // i*4+b
        long col = n0 + wc*64 + qc2*32 + (lane&31);                       // h*64+d
        size_t dst = (((size_t)(row&3)*16 + (col>>6))*1024 + (row>>2))*64 + (col&63);
        float a = acc[qr][qc2][e];
        QU[dst] = f2b(a + u[col]);
        QV[dst] = f2b(a + v[col]);
      }
}

// ---------------- fused attention v13 (K now from dedicated Kb[t*4+b][1024]) ----------------
__global__ __launch_bounds__(256,2) void flash_attn4(
    const unsigned short* __restrict__ QU, const unsigned short* __restrict__ QV,
    const unsigned short* __restrict__ Kb, const unsigned short* __restrict__ VT,
    const unsigned short* __restrict__ relo, unsigned short* __restrict__ AV)
{
  __shared__ __align__(16) unsigned short qv_s[65*72];
  __shared__ __align__(16) unsigned short k_s [2][64*64];   // XOR-64, double-buffered
  __shared__ __align__(16) unsigned short vt_s[64*64];      // XOR-64, single buffer
  __shared__ __align__(16) unsigned short rg_s[2][128*64];  // R window, double-buffered
  __shared__ __align__(16) unsigned short p_s [64*64];      // QU staging, then P (XOR-64)
  __shared__ float l_s[64];

  const int tid = threadIdx.x, lane = tid&63, wave = tid>>6;
  const int bh = blockIdx.x, b = bh>>4, h = bh&15;
  const int i0 = blockIdx.y*64;
  const int qr = wave>>1, qc = wave&1;
  const int hi = lane>>5, ll = lane&31;
  const unsigned short* QUb = QU + (size_t)bh*S_*DH_;
  const unsigned short* QVb = QV + (size_t)bh*S_*DH_;
  const unsigned short* Kg  = Kb + (size_t)b*1024 + h*64;            // + t*4096
  const unsigned short* VTb = VT + (size_t)bh*64*T_;
  const unsigned short* Rg  = relo + (size_t)b*1024 + h*64;          // + t*4096

  // per-thread staging geometry (2-chunk tiles: K, VT)
  const int s0r = tid>>3,        s0c = (((tid&7)       ^ (s0r&7)))*8;
  const int s1r = (256+tid)>>3,  s1c = ((((256+tid)&7) ^ (s1r&7)))*8;

  // ---- prologue: DMA K(0)->k_s[0], R(0)->rg_s[0]; stage QU->p_s, QV->qv_s ----
  glds16(&Kg [(size_t)(0+s0r)*4096 + s0c], &k_s[0][(size_t)tid*8]);
  glds16(&Kg [(size_t)(0+s1r)*4096 + s1c], &k_s[0][(size_t)(256+tid)*8]);
  {
    const int wb0 = 0 - i0 + 960;    // j0=0 is always cls 0
    for (int c=0;c<4;c++){
      int ch = c*256+tid; int rr = ch>>3, off = ch&7;
      int t = wb0 + rr; t = t < 0 ? 0 : (t > T_-1 ? T_-1 : t);
      glds16(&Rg[(size_t)t*4096 + ((off ^ (rr&7)))*8], &rg_s[0][(size_t)ch*8]);
    }
  }
  for (int c=0;c<2;c++){
    int ch = c*256+tid; int row = ch>>3, off=(ch&7);
    *(uint4*)&p_s[row*64 + ((off ^ (row&7))<<3)] = *(const uint4*)&QUb[(size_t)(i0+row)*64 + off*8];
    *(uint4*)&qv_s[row*72+off*8] = *(const uint4*)&QVb[(size_t)(i0+row)*64 + off*8];
  }
  if (tid < 8) {
    int rr = i0 + 64; if (rr > S_-1) rr = S_-1;
    *(uint4*)&qv_s[64*72 + tid*8] = *(const uint4*)&QVb[(size_t)rr*64 + tid*8];
  }
  BAR_L();   // QU/QV plain stores visible

  // ---- Q-hoist: j-invariant A-fragments into registers (32 VGPRs) ----
  s16x8 qur0, qur1, qur2, qur3;     // QU row qr*32+ll (from p_s XOR-64)
  s16x8 qv00, qv01, qv02, qv03;     // QV row qr*32+ll (shift 0)
  {
    const int rq = qr*32 + ll;
    qur0 = *(const s16x8*)&p_s[rq*64 + (((0*2+hi) ^ (rq&7))<<3)];
    qur1 = *(const s16x8*)&p_s[rq*64 + (((1*2+hi) ^ (rq&7))<<3)];
    qur2 = *(const s16x8*)&p_s[rq*64 + (((2*2+hi) ^ (rq&7))<<3)];
    qur3 = *(const s16x8*)&p_s[rq*64 + (((3*2+hi) ^ (rq&7))<<3)];
    const int ro = rq*72 + hi*8;
    qv00 = *(const s16x8*)&qv_s[ro +  0];
    qv01 = *(const s16x8*)&qv_s[ro + 16];
    qv02 = *(const s16x8*)&qv_s[ro + 32];
    qv03 = *(const s16x8*)&qv_s[ro + 48];
  }
  // (no barrier here: the first loop-top BAR_VL drains K/R(0) vmem and each
  //  wave's hoist lgkm reads before gather(0) can overwrite p_s)

  s16x8 ones;
  for (int e=0;e<8;e++) ones[e] = (short)0x3F80;   // bf16 1.0

  f32x16 acc_o, acc_l;
  for (int e=0;e<16;e++){ acc_o[e]=0.f; acc_l[e]=0.f; }

  const int col = qc*32 + ll;
  const int cbase = (qc - qr + 1) * 32;   // wave's band-quad column base

  int cur = 0;
  for (int j0 = 0; j0 < T_; j0 += 64) {
    const int jdmax = j0 + 63 - i0;
    const int jdmin = j0 - 63 - i0;
    const int cls = (jdmax <= 1024) ? 0 : ((jdmin >= 1026) ? 2 : 1);
    const int jn = j0 + 64;
    unsigned short* kc = &k_s[cur][0];
    unsigned short* rc = &rg_s[cur][0];
    unsigned short* kn = &k_s[cur^1][0];
    unsigned short* rn = &rg_s[cur^1][0];

    BAR_VL();                  // B1: PV(j-1)/hoist lgkm done; K(j)/R(j) landed

    // stage VT(j) FIRST (oldest vmem pair -> B3's counted drain targets it)
    glds16(&VTb[(size_t)s0r*T_ + j0 + s0c], &vt_s[(size_t)tid*8]);
    glds16(&VTb[(size_t)s1r*T_ + j0 + s1c], &vt_s[(size_t)(256+tid)*8]);
    // prefetch K/R(j+1) into the other buffers (no WAR: reads use buf[cur])
    if (jn < T_) {
      glds16(&Kg[(size_t)(jn+s0r)*4096 + s0c], &kn[(size_t)tid*8]);
      glds16(&Kg[(size_t)(jn+s1r)*4096 + s1c], &kn[(size_t)(256+tid)*8]);
      const int jdmaxn = jn + 63 - i0;
      const int jdminn = jn - 63 - i0;
      const int clsn = (jdmaxn <= 1024) ? 0 : ((jdminn >= 1026) ? 2 : 1);
      const int wbn = (clsn == 2) ? (jn - i0 - 1089) : (jn - i0 + 960);
      for (int c=0;c<4;c++){
        int ch = c*256+tid; int rr = ch>>3, off = ch&7;
        int t = wbn + rr; t = t < 0 ? 0 : (t > T_-1 ? T_-1 : t);
        glds16(&Rg[(size_t)t*4096 + ((off ^ (rr&7)))*8], &rn[(size_t)ch*8]);
      }
    }

    // band A-operand: hoisted shift-0 regs, or LDS shift-1 rows for cls2
    s16x8 av0, av1, av2, av3;
    if (cls == 2) {
      const int ro1 = (qr*32+ll+1)*72 + hi*8;
      av0 = *(const s16x8*)&qv_s[ro1 +  0];
      av1 = *(const s16x8*)&qv_s[ro1 + 16];
      av2 = *(const s16x8*)&qv_s[ro1 + 32];
      av3 = *(const s16x8*)&qv_s[ro1 + 48];
    } else {
      av0 = qv00; av1 = qv01; av2 = qv02; av3 = qv03;
    }

    // band GEMM: the wave's OWN 2 quads at cbase (kept in registers)
    f32x16 gacc0, gacc1;
    for (int e=0;e<16;e++){ gacc0[e]=0.f; gacc1[e]=0.f; }
    __builtin_amdgcn_s_setprio(1);
#define BANDK(KS, AV) { \
      int kb = KS*2 + hi; \
      { int br = cbase + ll; \
        s16x8 bb = *(const s16x8*)&rc[br*64 + ((kb ^ (br&7))<<3)]; \
        gacc0 = __builtin_amdgcn_mfma_f32_32x32x16_bf16(AV, bb, gacc0, 0,0,0); } \
      { int br = cbase + 32 + ll; \
        s16x8 bb = *(const s16x8*)&rc[br*64 + ((kb ^ (br&7))<<3)]; \
        gacc1 = __builtin_amdgcn_mfma_f32_32x32x16_bf16(AV, bb, gacc1, 0,0,0); } }
    BANDK(0, av0) BANDK(1, av1) BANDK(2, av2) BANDK(3, av3)

    // AC quad (hoisted qur, kc in XOR-64 layout)
    f32x16 acc;
    for (int e=0;e<16;e++) acc[e]=0.f;
#define ACK(KS, AU) { \
      int kb = KS*2 + hi; \
      int rbk = qc*32 + ll; \
      s16x8 bq = *(const s16x8*)&kc[rbk*64 + ((kb ^ (rbk&7))<<3)]; \
      acc = __builtin_amdgcn_mfma_f32_32x32x16_bf16(AU, bq, acc, 0,0,0); }
    ACK(0, qur0) ACK(1, qur1) ACK(2, qur2) ACK(3, qur3)
    __builtin_amdgcn_s_setprio(0);

    // in-register gather (select-then-permute, 16 bperm) + exp -> P (XOR-64)
    for (int e=0;e<16;e++){
      int rm = 4*hi + (e&3) + 8*(e>>2);     // r - qr*32
      int r  = qr*32 + rm;
      int jd = j0 + col - (i0 + r);
      int tl = (ll + rm + 1) & 31;          // target lane fed by this source
      float sel = (tl > rm) ? gacc1[e] : gacc0[e];
      int li = ((((ll - rm + 31) & 31) | (hi<<5)) << 2);
      float bd = __uint_as_float((unsigned)__builtin_amdgcn_ds_bpermute(li, (int)__float_as_uint(sel)));
      if (jd == 1025) bd = 0.f;
      float p = __expf((acc[e] + bd) * 0.125f);
      if (!(cls == 1 && jd >= 1026))
        p_s[r*64 + (((col>>3) ^ (r&7))<<3) + (col&7)] = f2b(p);
    }

    if (cls == 1) {
      BAR_L();                 // C1: all waves' band reads of rc done
      // stage wrap R window into rc (dead after band)
      const int wb2 = j0 - i0 - 1089;
      for (int c=0;c<4;c++){
        int ch = c*256+tid; int rr = ch>>3, off = ch&7;
        int t = wb2 + rr; t = t < 0 ? 0 : (t > T_-1 ? T_-1 : t);
        glds16(&Rg[(size_t)t*4096 + ((off ^ (rr&7)))*8], &rc[(size_t)ch*8]);
      }
      BAR_VL();                // C2: wrap R landed (drains VT/K/R(j+1) too; 1x per block)
      f32x16 g2a, g2b;
      for (int e=0;e<16;e++){ g2a[e]=0.f; g2b[e]=0.f; }
      __builtin_amdgcn_s_setprio(1);
#define BANDW(KS) { \
        int kb = KS*2 + hi; \
        const int ro1 = (qr*32+ll+1)*72 + hi*8; \
        s16x8 a = *(const s16x8*)&qv_s[ro1 + KS*16]; \
        { int br = cbase + ll; \
          s16x8 bb = *(const s16x8*)&rc[br*64 + ((kb ^ (br&7))<<3)]; \
          g2a = __builtin_amdgcn_mfma_f32_32x32x16_bf16(a, bb, g2a, 0,0,0); } \
        { int br = cbase + 32 + ll; \
          s16x8 bb = *(const s16x8*)&rc[br*64 + ((kb ^ (br&7))<<3)]; \
          g2b = __builtin_amdgcn_mfma_f32_32x32x16_bf16(a, bb, g2b, 0,0,0); } }
      BANDW(0) BANDW(1) BANDW(2) BANDW(3)
      __builtin_amdgcn_s_setprio(0);
      for (int e=0;e<16;e++){
        int rm = 4*hi + (e&3) + 8*(e>>2);
        int r  = qr*32 + rm;
        int jd = j0 + col - (i0 + r);
        int tl = (ll + rm + 1) & 31;
        float sel = (tl > rm) ? g2b[e] : g2a[e];
        int li = ((((ll - rm + 31) & 31) | (hi<<5)) << 2);
        float bd = __uint_as_float((unsigned)__builtin_amdgcn_ds_bpermute(li, (int)__float_as_uint(sel)));
        float p = __expf((acc[e] + bd) * 0.125f);
        if (jd >= 1026)
          p_s[r*64 + (((col>>3) ^ (r&7))<<3) + (col&7)] = f2b(p);
      }
    }

    // B3: P visible; VT(j) landed (counted: K/R(j+1) stay in flight).
    // cls1 already fully drained at C2 -> vmcnt(6) is a no-op there.
    if (jn < T_) { BAR_V6L(); } else { BAR_VL(); }

    // PV quad + MFMA rowsum (A-fragments from p_s XOR-64)
    __builtin_amdgcn_s_setprio(1);
    for (int ks=0; ks<4; ks++){
      int kb = ks*2 + hi;
      int rv = qr*32 + ll, rbv = qc*32 + ll;
      s16x8 a  = *(const s16x8*)&p_s[rv*64 + ((kb ^ (rv&7))<<3)];
      s16x8 bv = *(const s16x8*)&vt_s[rbv*64 + ((kb ^ (rbv&7))<<3)];
      acc_o = __builtin_amdgcn_mfma_f32_32x32x16_bf16(a, bv, acc_o, 0,0,0);
      acc_l = __builtin_amdgcn_mfma_f32_32x32x16_bf16(a, ones, acc_l, 0,0,0);
    }
    __builtin_amdgcn_s_setprio(0);
    cur ^= 1;
    // no trailing barrier: loop-top B1 orders everything
  }

  // epilogue: l from acc_l (every lane's acc_l[e] = rowsum of row r)
  if (qc == 0 && ll == 0) {
    for (int e=0;e<16;e++){
      int r = qr*32 + 4*hi + (e&3) + 8*(e>>2);
      l_s[r] = acc_l[e];
    }
  }
  BAR_L();
  for (int e=0;e<16;e++){
    int r = qr*32 + 4*hi + (e&3) + 8*(e>>2);
    float oo = acc_o[e] / l_s[r];
    AV[ ((size_t)(i0+r)*B_ + b)*(H_*DH_) + h*DH_ + col ] = f2b(oo);
  }
#undef BANDK
#undef ACK
#undef BANDW
}

// ---------------- LayerNorm ----------------
__global__ __launch_bounds__(256) void ln_kernel(const float* __restrict__ y,
    const float* __restrict__ g, const float* __restrict__ be, float* __restrict__ o)
{
  __shared__ float red[8];
  int row = blockIdx.x, tid = threadIdx.x;
  const float* yr = y + (size_t)row*DM_;
  float v[4];
  for (int e=0;e<4;e++) v[e] = yr[tid + 256*e];
  float s = v[0]+v[1]+v[2]+v[3];
  for (int off=32; off>0; off>>=1) s += __shfl_down(s, off, 64);
  if ((tid&63)==0) red[tid>>6] = s;
  __syncthreads();
  if (tid==0) red[4] = red[0]+red[1]+red[2]+red[3];
  __syncthreads();
  float mu = red[4] * (1.f/DM_);
  __syncthreads();
  float q = 0.f;
  for (int e=0;e<4;e++){ float d = v[e]-mu; q += d*d; }
  for (int off=32; off>0; off>>=1) q += __shfl_down(q, off, 64);
  if ((tid&63)==0) red[tid>>6] = q;
  __syncthreads();
  if (tid==0) red[4] = red[0]+red[1]+red[2]+red[3];
  __syncthreads();
  float rstd = rsqrtf(red[4]*(1.f/DM_) + 1e-5f);
  for (int e=0;e<4;e++){
    int c = tid + 256*e;
    o[(size_t)row*DM_ + c] = g[c]*(v[e]-mu)*rstd + be[c];
  }
}

// ---------------- launch ----------------
extern "C" void kernel_launch(void* const* d_in, const int* in_sizes, int n_in,
                              void* d_out, int out_size, void* d_ws, size_t ws_size,
                              hipStream_t stream)
{
  const float* x    = (const float*)d_in[0];
  const float* mem  = (const float*)d_in[1];
  const float* pos  = (const float*)d_in[2];
  const float* pbu  = (const float*)d_in[3];
  const float* pbv  = (const float*)d_in[4];
  const float* wqkv = (const float*)d_in[5];
  const float* wrel = (const float*)d_in[6];
  const float* wo   = (const float*)d_in[7];
  const float* gam  = (const float*)d_in[8];
  const float* bet  = (const float*)d_in[9];
  float* out = (float*)d_out;

  char* w = (char*)d_ws;
  unsigned short* Kb    = (unsigned short*)(w + 0);          // 16,777,216
  unsigned short* relo  = (unsigned short*)(w + 16777216);   // 16,777,216
  unsigned short* wo16  = (unsigned short*)(w + 33554432);   //  2,097,152
  unsigned short* QUb   = (unsigned short*)(w + 35651584);   //  8,388,608
  unsigned short* QVb   = (unsigned short*)(w + 44040192);   //  8,388,608
  unsigned short* VT    = (unsigned short*)(w + 52428800);   // 16,777,216
  unsigned short* av16  = (unsigned short*)(w + 69206016);   //  8,388,608
  float*          yf    = (float*)(w + 77594624);            // 16,777,216
  unsigned short* c16   = (unsigned short*)(w + 94371840);   // 16,777,216
  unsigned short* pos16 = (unsigned short*)(w + 111149056);  // 16,777,216
  unsigned short* wq16  = (unsigned short*)(w + 127926272);  //  6,291,456
  unsigned short* wr16  = (unsigned short*)(w + 134217728);  //  2,097,152 -> total 136,314,880

  cast_all<<<10752, 256, 0, stream>>>(mem, x, pos, wqkv, wrel, wo,
                                      c16, pos16, wq16, wr16, wo16);

  // K-GEMM: all T rows x K-weight cols -> Kb[t*4+b][1024]
  gemm_nt<<<dim3(8,64), 256, 0, stream>>>(c16, wq16 + (size_t)1024*1024,
                                          (void*)Kb, nullptr, 1024, 1024, 0);
  // V-GEMM: writes V^T directly (per-batch via blockIdx.z) -> VT
  gemm_vt<<<dim3(16,8,4), 256, 0, stream>>>(wq16 + (size_t)2048*1024, c16, VT);
  // Q-GEMM: x rows only, fused u/v bias -> QU/QV per-head layout
  gemm_q<<<dim3(8,32), 256, 0, stream>>>(c16 + (size_t)4096*1024, wq16,
                                         pbu, pbv, QUb, QVb);
  // rel GEMM
  gemm_nt<<<dim3(8,64), 256, 0, stream>>>(pos16, wr16, (void*)relo, nullptr, 1024, 1024, 0);

  flash_attn4<<<dim3(64,16), 256, 0, stream>>>(QUb, QVb, Kb, VT, relo, av16);

  gemm_nt<<<dim3(8,32), 256, 0, stream>>>(av16, wo16, (void*)yf, x, 1024, 1024, 1);
  ln_kernel<<<4096, 256, 0, stream>>>(yf, gam, bet, out);
}

// Round 12
// 439.082 us; speedup vs baseline: 1.0725x; 1.0375x over previous
//
#include <hip/hip_runtime.h>

#define S_ 1024
#define M_ 1024
#define T_ 2048
#define B_ 4
#define H_ 16
#define DM_ 1024
#define DH_ 64

typedef __attribute__((ext_vector_type(8))) short s16x8;
typedef __attribute__((ext_vector_type(16))) float f32x16;

__device__ __forceinline__ unsigned short f2b(float x){
  unsigned int u = __float_as_uint(x);
  u = (u + 0x7fffu + ((u>>16)&1u)) >> 16;
  return (unsigned short)u;
}
__device__ __forceinline__ float b2f(unsigned short h){
  return __uint_as_float(((unsigned int)h)<<16);
}
__device__ __forceinline__ uint4 pack8(const float* v){
  uint4 o;
  o.x = (unsigned)f2b(v[0]) | ((unsigned)f2b(v[1])<<16);
  o.y = (unsigned)f2b(v[2]) | ((unsigned)f2b(v[3])<<16);
  o.z = (unsigned)f2b(v[4]) | ((unsigned)f2b(v[5])<<16);
  o.w = (unsigned)f2b(v[6]) | ((unsigned)f2b(v[7])<<16);
  return o;
}
__device__ __forceinline__ void glds16(const unsigned short* g, unsigned short* l){
  __builtin_amdgcn_global_load_lds((const __attribute__((address_space(1))) void*)g,
                                   (__attribute__((address_space(3))) void*)l, 16, 0, 0);
}

// raw barriers:
//   BAR_L   waits only LDS ops (glds prefetches stay in flight)
//   BAR_VL  drains vmcnt fully
//   BAR_V6L counted drain: waits for the 2 OLDEST vmem ops (VT of this iter),
//           leaves the 6 newer K/R(j+1) prefetches in flight (T4).
#define BAR_L()   asm volatile("s_waitcnt lgkmcnt(0)\ns_barrier" ::: "memory")
#define BAR_VL()  asm volatile("s_waitcnt vmcnt(0) lgkmcnt(0)\ns_barrier" ::: "memory")
#define BAR_V6L() asm volatile("s_waitcnt vmcnt(6) lgkmcnt(0)\ns_barrier" ::: "memory")

// ---------------- fused cast kernel ----------------
__global__ __launch_bounds__(256) void cast_all(
    const float* __restrict__ mem, const float* __restrict__ x,
    const float* __restrict__ pos, const float* __restrict__ wqkv,
    const float* __restrict__ wrel, const float* __restrict__ wo,
    unsigned short* __restrict__ c16, unsigned short* __restrict__ pos16,
    unsigned short* __restrict__ wq16, unsigned short* __restrict__ wr16,
    unsigned short* __restrict__ wo16)
{
  int u = blockIdx.x*256 + threadIdx.x;
  const float* s; unsigned short* d;
  if (u < 1048576)      { s = (u < 524288) ? mem + (size_t)u*8 : x + (size_t)(u-524288)*8;
                          d = c16 + (size_t)u*8; }
  else if (u < 2097152) { int v = u - 1048576; s = pos  + (size_t)v*8; d = pos16 + (size_t)v*8; }
  else if (u < 2490368) { int v = u - 2097152; s = wqkv + (size_t)v*8; d = wq16  + (size_t)v*8; }
  else if (u < 2621440) { int v = u - 2490368; s = wrel + (size_t)v*8; d = wr16  + (size_t)v*8; }
  else                  { int v = u - 2621440; s = wo   + (size_t)v*8; d = wo16  + (size_t)v*8; }
  float4 x0 = *(const float4*)s;
  float4 x1 = *(const float4*)(s+4);
  float f[8] = {x0.x,x0.y,x0.z,x0.w,x1.x,x1.y,x1.z,x1.w};
  *(uint4*)d = pack8(f);
}

// ---------------- GEMM: C[M][N] = A[M][K] @ B[N][K]^T  (bf16 in, NT) ----------------
__global__ __launch_bounds__(256) void gemm_nt(const unsigned short* __restrict__ A,
    const unsigned short* __restrict__ Bw, void* __restrict__ Cout,
    const float* __restrict__ res, int Ntot, int K, int mode)
{
  __shared__ __align__(16) unsigned short a_s[128*64];
  __shared__ __align__(16) unsigned short b_s[128*64];
  const int tid = threadIdx.x;
  const int lane = tid & 63, wave = tid >> 6;
  const int wr = wave >> 1, wc = wave & 1;
  const long m0 = (long)blockIdx.y * 128, n0 = (long)blockIdx.x * 128;
  f32x16 acc[2][2];
  for (int qa=0;qa<2;qa++) for(int qb=0;qb<2;qb++) for (int e=0;e<16;e++) acc[qa][qb][e]=0.f;
  int srow[4], scol[4];
  for (int c = 0; c < 4; c++) {
    int ch = c*256 + tid;
    srow[c] = ch >> 3;
    scol[c] = (((ch & 7) ^ (srow[c] & 7))) * 8;
  }
  for (int k0 = 0; k0 < K; k0 += 64) {
    for (int c = 0; c < 4; c++) {
      int ch = c*256 + tid;
      glds16(&A[(size_t)(m0+srow[c])*K + k0 + scol[c]], &a_s[ch*8]);
      glds16(&Bw[(size_t)(n0+srow[c])*K + k0 + scol[c]], &b_s[ch*8]);
    }
    __syncthreads();
    for (int ks = 0; ks < 4; ks++) {
      const int kb = ks*2 + (lane>>5);
      s16x8 af[2], bf[2];
      for (int q = 0; q < 2; q++) {
        int ra = wr*64 + q*32 + (lane&31);
        int rb = wc*64 + q*32 + (lane&31);
        af[q] = *(const s16x8*)&a_s[ra*64 + ((kb ^ (ra&7))<<3)];
        bf[q] = *(const s16x8*)&b_s[rb*64 + ((kb ^ (rb&7))<<3)];
      }
      for (int qr=0;qr<2;qr++)
        for (int qc2=0;qc2<2;qc2++)
          acc[qr][qc2] = __builtin_amdgcn_mfma_f32_32x32x16_bf16(af[qr], bf[qc2], acc[qr][qc2], 0,0,0);
    }
    __syncthreads();
  }
  for (int qr=0;qr<2;qr++)
    for (int qc2=0;qc2<2;qc2++)
      for (int e=0;e<16;e++){
        long row = m0 + wr*64 + qr*32 + (e&3) + 8*(e>>2) + 4*(lane>>5);
        long col = n0 + wc*64 + qc2*32 + (lane&31);
        size_t o = (size_t)row*Ntot + col;
        if (mode == 0) ((unsigned short*)Cout)[o] = f2b(acc[qr][qc2][e]);
        else           ((float*)Cout)[o] = acc[qr][qc2][e] + res[o];
      }
}

// ---------------- fused 4-role GEMM (K / rel / Q / V^T in ONE dispatch) ----------------
// role 0: blocks [0,512)     K-GEMM   A=c16            B=wq16+1M   -> Kb  (u16, N=1024)
// role 1: blocks [512,1024)  rel-GEMM A=pos16          B=wr16      -> relo(u16, N=1024)
// role 2: blocks [1024,1280) Q-GEMM   A=c16+4096*1024  B=wq16      -> QU/QV (+u/v bias)
// role 3: blocks [1280,1792) V-GEMM   A=wq16+2M        B=c16(t*4+bz) -> VT (transposed)
__global__ __launch_bounds__(256) void gemm4(
    const unsigned short* __restrict__ c16, const unsigned short* __restrict__ pos16,
    const unsigned short* __restrict__ wq16, const unsigned short* __restrict__ wr16,
    const float* __restrict__ u, const float* __restrict__ v,
    unsigned short* __restrict__ Kb, unsigned short* __restrict__ relo,
    unsigned short* __restrict__ QU, unsigned short* __restrict__ QV,
    unsigned short* __restrict__ VT)
{
  __shared__ __align__(16) unsigned short a_s[128*64];
  __shared__ __align__(16) unsigned short b_s[128*64];
  const int tid = threadIdx.x;
  const int lane = tid & 63, wave = tid >> 6;
  const int wr = wave >> 1, wc = wave & 1;

  const int id = blockIdx.x;
  int role, bx, by, bz = 0;
  if      (id < 512)  { role = 0; bx = id & 7;  by = id >> 3; }
  else if (id < 1024) { role = 1; int t = id - 512;  bx = t & 7;  by = t >> 3; }
  else if (id < 1280) { role = 2; int t = id - 1024; bx = t & 7;  by = t >> 3; }
  else                { role = 3; int t = id - 1280; bx = t & 15; by = (t >> 4) & 7; bz = t >> 7; }
  const long m0 = (long)by * 128, n0 = (long)bx * 128;

  const unsigned short* A  = (role==0) ? c16 :
                             (role==1) ? pos16 :
                             (role==2) ? c16 + (size_t)4096*1024 :
                                         wq16 + (size_t)2048*1024;
  const unsigned short* Bw = (role==0) ? wq16 + (size_t)1024*1024 :
                             (role==1) ? wr16 :
                             (role==2) ? wq16 : c16;

  f32x16 acc[2][2];
  for (int qa=0;qa<2;qa++) for(int qb=0;qb<2;qb++) for (int e=0;e<16;e++) acc[qa][qb][e]=0.f;

  // per-chunk base offsets (k0 added in-loop). B addressing: roles 0-2 use
  // row*1024; role 3 uses (row*4+bz)*1024 (batch-interleaved c16 rows).
  size_t aOff[4], bOff[4];
  for (int c = 0; c < 4; c++) {
    int ch = c*256 + tid;
    int srow = ch >> 3;
    int scol = ((ch & 7) ^ (srow & 7)) * 8;
    aOff[c] = (size_t)(m0+srow)*1024 + scol;
    bOff[c] = (role==3) ? (((size_t)(n0+srow)*4 + bz)*1024 + scol)
                        : ((size_t)(n0+srow)*1024 + scol);
  }

  for (int k0 = 0; k0 < 1024; k0 += 64) {
    for (int c = 0; c < 4; c++) {
      int ch = c*256 + tid;
      glds16(&A [aOff[c] + k0], &a_s[ch*8]);
      glds16(&Bw[bOff[c] + k0], &b_s[ch*8]);
    }
    __syncthreads();
    for (int ks = 0; ks < 4; ks++) {
      const int kb = ks*2 + (lane>>5);
      s16x8 af[2], bf[2];
      for (int q = 0; q < 2; q++) {
        int ra = wr*64 + q*32 + (lane&31);
        int rb = wc*64 + q*32 + (lane&31);
        af[q] = *(const s16x8*)&a_s[ra*64 + ((kb ^ (ra&7))<<3)];
        bf[q] = *(const s16x8*)&b_s[rb*64 + ((kb ^ (rb&7))<<3)];
      }
      for (int qr=0;qr<2;qr++)
        for (int qc2=0;qc2<2;qc2++)
          acc[qr][qc2] = __builtin_amdgcn_mfma_f32_32x32x16_bf16(af[qr], bf[qc2], acc[qr][qc2], 0,0,0);
    }
    __syncthreads();
  }

  for (int qr=0;qr<2;qr++)
    for (int qc2=0;qc2<2;qc2++)
      for (int e=0;e<16;e++){
        long row = m0 + wr*64 + qr*32 + (e&3) + 8*(e>>2) + 4*(lane>>5);
        long col = n0 + wc*64 + qc2*32 + (lane&31);
        float a = acc[qr][qc2][e];
        if (role == 0)      Kb  [(size_t)row*1024 + col] = f2b(a);
        else if (role == 1) relo[(size_t)row*1024 + col] = f2b(a);
        else if (role == 2) {
          // row = i*4+b, col = h*64+d -> dst = ((b*16+h)*1024 + i)*64 + d
          size_t dst = (((size_t)(row&3)*16 + (col>>6))*1024 + (row>>2))*64 + (col&63);
          QU[dst] = f2b(a + u[col]);
          QV[dst] = f2b(a + v[col]);
        } else {
          // row = i (h*64+d), col = t -> VT[bz*2M + row*2048 + col]
          VT[(size_t)bz*2097152 + (size_t)row*2048 + col] = f2b(a);
        }
      }
}

// ---------------- fused attention v13 (unchanged; verified) ----------------
__global__ __launch_bounds__(256,2) void flash_attn4(
    const unsigned short* __restrict__ QU, const unsigned short* __restrict__ QV,
    const unsigned short* __restrict__ Kb, const unsigned short* __restrict__ VT,
    const unsigned short* __restrict__ relo, unsigned short* __restrict__ AV)
{
  __shared__ __align__(16) unsigned short qv_s[65*72];
  __shared__ __align__(16) unsigned short k_s [2][64*64];   // XOR-64, double-buffered
  __shared__ __align__(16) unsigned short vt_s[64*64];      // XOR-64, single buffer
  __shared__ __align__(16) unsigned short rg_s[2][128*64];  // R window, double-buffered
  __shared__ __align__(16) unsigned short p_s [64*64];      // QU staging, then P (XOR-64)
  __shared__ float l_s[64];

  const int tid = threadIdx.x, lane = tid&63, wave = tid>>6;
  const int bh = blockIdx.x, b = bh>>4, h = bh&15;
  const int i0 = blockIdx.y*64;
  const int qr = wave>>1, qc = wave&1;
  const int hi = lane>>5, ll = lane&31;
  const unsigned short* QUb = QU + (size_t)bh*S_*DH_;
  const unsigned short* QVb = QV + (size_t)bh*S_*DH_;
  const unsigned short* Kg  = Kb + (size_t)b*1024 + h*64;            // + t*4096
  const unsigned short* VTb = VT + (size_t)bh*64*T_;
  const unsigned short* Rg  = relo + (size_t)b*1024 + h*64;          // + t*4096

  // per-thread staging geometry (2-chunk tiles: K, VT)
  const int s0r = tid>>3,        s0c = (((tid&7)       ^ (s0r&7)))*8;
  const int s1r = (256+tid)>>3,  s1c = ((((256+tid)&7) ^ (s1r&7)))*8;

  // ---- prologue: DMA K(0)->k_s[0], R(0)->rg_s[0]; stage QU->p_s, QV->qv_s ----
  glds16(&Kg [(size_t)(0+s0r)*4096 + s0c], &k_s[0][(size_t)tid*8]);
  glds16(&Kg [(size_t)(0+s1r)*4096 + s1c], &k_s[0][(size_t)(256+tid)*8]);
  {
    const int wb0 = 0 - i0 + 960;    // j0=0 is always cls 0
    for (int c=0;c<4;c++){
      int ch = c*256+tid; int rr = ch>>3, off = ch&7;
      int t = wb0 + rr; t = t < 0 ? 0 : (t > T_-1 ? T_-1 : t);
      glds16(&Rg[(size_t)t*4096 + ((off ^ (rr&7)))*8], &rg_s[0][(size_t)ch*8]);
    }
  }
  for (int c=0;c<2;c++){
    int ch = c*256+tid; int row = ch>>3, off=(ch&7);
    *(uint4*)&p_s[row*64 + ((off ^ (row&7))<<3)] = *(const uint4*)&QUb[(size_t)(i0+row)*64 + off*8];
    *(uint4*)&qv_s[row*72+off*8] = *(const uint4*)&QVb[(size_t)(i0+row)*64 + off*8];
  }
  if (tid < 8) {
    int rr = i0 + 64; if (rr > S_-1) rr = S_-1;
    *(uint4*)&qv_s[64*72 + tid*8] = *(const uint4*)&QVb[(size_t)rr*64 + tid*8];
  }
  BAR_L();   // QU/QV plain stores visible

  // ---- Q-hoist: j-invariant A-fragments into registers (32 VGPRs) ----
  s16x8 qur0, qur1, qur2, qur3;     // QU row qr*32+ll (from p_s XOR-64)
  s16x8 qv00, qv01, qv02, qv03;     // QV row qr*32+ll (shift 0)
  {
    const int rq = qr*32 + ll;
    qur0 = *(const s16x8*)&p_s[rq*64 + (((0*2+hi) ^ (rq&7))<<3)];
    qur1 = *(const s16x8*)&p_s[rq*64 + (((1*2+hi) ^ (rq&7))<<3)];
    qur2 = *(const s16x8*)&p_s[rq*64 + (((2*2+hi) ^ (rq&7))<<3)];
    qur3 = *(const s16x8*)&p_s[rq*64 + (((3*2+hi) ^ (rq&7))<<3)];
    const int ro = rq*72 + hi*8;
    qv00 = *(const s16x8*)&qv_s[ro +  0];
    qv01 = *(const s16x8*)&qv_s[ro + 16];
    qv02 = *(const s16x8*)&qv_s[ro + 32];
    qv03 = *(const s16x8*)&qv_s[ro + 48];
  }
  // (no barrier here: the first loop-top BAR_VL drains K/R(0) vmem and each
  //  wave's hoist lgkm reads before gather(0) can overwrite p_s)

  s16x8 ones;
  for (int e=0;e<8;e++) ones[e] = (short)0x3F80;   // bf16 1.0

  f32x16 acc_o, acc_l;
  for (int e=0;e<16;e++){ acc_o[e]=0.f; acc_l[e]=0.f; }

  const int col = qc*32 + ll;
  const int cbase = (qc - qr + 1) * 32;   // wave's band-quad column base

  int cur = 0;
  for (int j0 = 0; j0 < T_; j0 += 64) {
    const int jdmax = j0 + 63 - i0;
    const int jdmin = j0 - 63 - i0;
    const int cls = (jdmax <= 1024) ? 0 : ((jdmin >= 1026) ? 2 : 1);
    const int jn = j0 + 64;
    unsigned short* kc = &k_s[cur][0];
    unsigned short* rc = &rg_s[cur][0];
    unsigned short* kn = &k_s[cur^1][0];
    unsigned short* rn = &rg_s[cur^1][0];

    BAR_VL();                  // B1: PV(j-1)/hoist lgkm done; K(j)/R(j) landed

    // stage VT(j) FIRST (oldest vmem pair -> B3's counted drain targets it)
    glds16(&VTb[(size_t)s0r*T_ + j0 + s0c], &vt_s[(size_t)tid*8]);
    glds16(&VTb[(size_t)s1r*T_ + j0 + s1c], &vt_s[(size_t)(256+tid)*8]);
    // prefetch K/R(j+1) into the other buffers (no WAR: reads use buf[cur])
    if (jn < T_) {
      glds16(&Kg[(size_t)(jn+s0r)*4096 + s0c], &kn[(size_t)tid*8]);
      glds16(&Kg[(size_t)(jn+s1r)*4096 + s1c], &kn[(size_t)(256+tid)*8]);
      const int jdmaxn = jn + 63 - i0;
      const int jdminn = jn - 63 - i0;
      const int clsn = (jdmaxn <= 1024) ? 0 : ((jdminn >= 1026) ? 2 : 1);
      const int wbn = (clsn == 2) ? (jn - i0 - 1089) : (jn - i0 + 960);
      for (int c=0;c<4;c++){
        int ch = c*256+tid; int rr = ch>>3, off = ch&7;
        int t = wbn + rr; t = t < 0 ? 0 : (t > T_-1 ? T_-1 : t);
        glds16(&Rg[(size_t)t*4096 + ((off ^ (rr&7)))*8], &rn[(size_t)ch*8]);
      }
    }

    // band A-operand: hoisted shift-0 regs, or LDS shift-1 rows for cls2
    s16x8 av0, av1, av2, av3;
    if (cls == 2) {
      const int ro1 = (qr*32+ll+1)*72 + hi*8;
      av0 = *(const s16x8*)&qv_s[ro1 +  0];
      av1 = *(const s16x8*)&qv_s[ro1 + 16];
      av2 = *(const s16x8*)&qv_s[ro1 + 32];
      av3 = *(const s16x8*)&qv_s[ro1 + 48];
    } else {
      av0 = qv00; av1 = qv01; av2 = qv02; av3 = qv03;
    }

    // band GEMM: the wave's OWN 2 quads at cbase (kept in registers)
    f32x16 gacc0, gacc1;
    for (int e=0;e<16;e++){ gacc0[e]=0.f; gacc1[e]=0.f; }
    __builtin_amdgcn_s_setprio(1);
#define BANDK(KS, AV) { \
      int kb = KS*2 + hi; \
      { int br = cbase + ll; \
        s16x8 bb = *(const s16x8*)&rc[br*64 + ((kb ^ (br&7))<<3)]; \
        gacc0 = __builtin_amdgcn_mfma_f32_32x32x16_bf16(AV, bb, gacc0, 0,0,0); } \
      { int br = cbase + 32 + ll; \
        s16x8 bb = *(const s16x8*)&rc[br*64 + ((kb ^ (br&7))<<3)]; \
        gacc1 = __builtin_amdgcn_mfma_f32_32x32x16_bf16(AV, bb, gacc1, 0,0,0); } }
    BANDK(0, av0) BANDK(1, av1) BANDK(2, av2) BANDK(3, av3)

    // AC quad (hoisted qur, kc in XOR-64 layout)
    f32x16 acc;
    for (int e=0;e<16;e++) acc[e]=0.f;
#define ACK(KS, AU) { \
      int kb = KS*2 + hi; \
      int rbk = qc*32 + ll; \
      s16x8 bq = *(const s16x8*)&kc[rbk*64 + ((kb ^ (rbk&7))<<3)]; \
      acc = __builtin_amdgcn_mfma_f32_32x32x16_bf16(AU, bq, acc, 0,0,0); }
    ACK(0, qur0) ACK(1, qur1) ACK(2, qur2) ACK(3, qur3)
    __builtin_amdgcn_s_setprio(0);

    // in-register gather (select-then-permute, 16 bperm) + exp -> P (XOR-64)
    for (int e=0;e<16;e++){
      int rm = 4*hi + (e&3) + 8*(e>>2);     // r - qr*32
      int r  = qr*32 + rm;
      int jd = j0 + col - (i0 + r);
      int tl = (ll + rm + 1) & 31;          // target lane fed by this source
      float sel = (tl > rm) ? gacc1[e] : gacc0[e];
      int li = ((((ll - rm + 31) & 31) | (hi<<5)) << 2);
      float bd = __uint_as_float((unsigned)__builtin_amdgcn_ds_bpermute(li, (int)__float_as_uint(sel)));
      if (jd == 1025) bd = 0.f;
      float p = __expf((acc[e] + bd) * 0.125f);
      if (!(cls == 1 && jd >= 1026))
        p_s[r*64 + (((col>>3) ^ (r&7))<<3) + (col&7)] = f2b(p);
    }

    if (cls == 1) {
      BAR_L();                 // C1: all waves' band reads of rc done
      // stage wrap R window into rc (dead after band)
      const int wb2 = j0 - i0 - 1089;
      for (int c=0;c<4;c++){
        int ch = c*256+tid; int rr = ch>>3, off = ch&7;
        int t = wb2 + rr; t = t < 0 ? 0 : (t > T_-1 ? T_-1 : t);
        glds16(&Rg[(size_t)t*4096 + ((off ^ (rr&7)))*8], &rc[(size_t)ch*8]);
      }
      BAR_VL();                // C2: wrap R landed (drains VT/K/R(j+1) too; 1x per block)
      f32x16 g2a, g2b;
      for (int e=0;e<16;e++){ g2a[e]=0.f; g2b[e]=0.f; }
      __builtin_amdgcn_s_setprio(1);
#define BANDW(KS) { \
        int kb = KS*2 + hi; \
        const int ro1 = (qr*32+ll+1)*72 + hi*8; \
        s16x8 a = *(const s16x8*)&qv_s[ro1 + KS*16]; \
        { int br = cbase + ll; \
          s16x8 bb = *(const s16x8*)&rc[br*64 + ((kb ^ (br&7))<<3)]; \
          g2a = __builtin_amdgcn_mfma_f32_32x32x16_bf16(a, bb, g2a, 0,0,0); } \
        { int br = cbase + 32 + ll; \
          s16x8 bb = *(const s16x8*)&rc[br*64 + ((kb ^ (br&7))<<3)]; \
          g2b = __builtin_amdgcn_mfma_f32_32x32x16_bf16(a, bb, g2b, 0,0,0); } }
      BANDW(0) BANDW(1) BANDW(2) BANDW(3)
      __builtin_amdgcn_s_setprio(0);
      for (int e=0;e<16;e++){
        int rm = 4*hi + (e&3) + 8*(e>>2);
        int r  = qr*32 + rm;
        int jd = j0 + col - (i0 + r);
        int tl = (ll + rm + 1) & 31;
        float sel = (tl > rm) ? g2b[e] : g2a[e];
        int li = ((((ll - rm + 31) & 31) | (hi<<5)) << 2);
        float bd = __uint_as_float((unsigned)__builtin_amdgcn_ds_bpermute(li, (int)__float_as_uint(sel)));
        float p = __expf((acc[e] + bd) * 0.125f);
        if (jd >= 1026)
          p_s[r*64 + (((col>>3) ^ (r&7))<<3) + (col&7)] = f2b(p);
      }
    }

    // B3: P visible; VT(j) landed (counted: K/R(j+1) stay in flight).
    // cls1 already fully drained at C2 -> vmcnt(6) is a no-op there.
    if (jn < T_) { BAR_V6L(); } else { BAR_VL(); }

    // PV quad + MFMA rowsum (A-fragments from p_s XOR-64)
    __builtin_amdgcn_s_setprio(1);
    for (int ks=0; ks<4; ks++){
      int kb = ks*2 + hi;
      int rv = qr*32 + ll, rbv = qc*32 + ll;
      s16x8 a  = *(const s16x8*)&p_s[rv*64 + ((kb ^ (rv&7))<<3)];
      s16x8 bv = *(const s16x8*)&vt_s[rbv*64 + ((kb ^ (rbv&7))<<3)];
      acc_o = __builtin_amdgcn_mfma_f32_32x32x16_bf16(a, bv, acc_o, 0,0,0);
      acc_l = __builtin_amdgcn_mfma_f32_32x32x16_bf16(a, ones, acc_l, 0,0,0);
    }
    __builtin_amdgcn_s_setprio(0);
    cur ^= 1;
    // no trailing barrier: loop-top B1 orders everything
  }

  // epilogue: l from acc_l (every lane's acc_l[e] = rowsum of row r)
  if (qc == 0 && ll == 0) {
    for (int e=0;e<16;e++){
      int r = qr*32 + 4*hi + (e&3) + 8*(e>>2);
      l_s[r] = acc_l[e];
    }
  }
  BAR_L();
  for (int e=0;e<16;e++){
    int r = qr*32 + 4*hi + (e&3) + 8*(e>>2);
    float oo = acc_o[e] / l_s[r];
    AV[ ((size_t)(i0+r)*B_ + b)*(H_*DH_) + h*DH_ + col ] = f2b(oo);
  }
#undef BANDK
#undef ACK
#undef BANDW
}

// ---------------- LayerNorm ----------------
__global__ __launch_bounds__(256) void ln_kernel(const float* __restrict__ y,
    const float* __restrict__ g, const float* __restrict__ be, float* __restrict__ o)
{
  __shared__ float red[8];
  int row = blockIdx.x, tid = threadIdx.x;
  const float* yr = y + (size_t)row*DM_;
  float v[4];
  for (int e=0;e<4;e++) v[e] = yr[tid + 256*e];
  float s = v[0]+v[1]+v[2]+v[3];
  for (int off=32; off>0; off>>=1) s += __shfl_down(s, off, 64);
  if ((tid&63)==0) red[tid>>6] = s;
  __syncthreads();
  if (tid==0) red[4] = red[0]+red[1]+red[2]+red[3];
  __syncthreads();
  float mu = red[4] * (1.f/DM_);
  __syncthreads();
  float q = 0.f;
  for (int e=0;e<4;e++){ float d = v[e]-mu; q += d*d; }
  for (int off=32; off>0; off>>=1) q += __shfl_down(q, off, 64);
  if ((tid&63)==0) red[tid>>6] = q;
  __syncthreads();
  if (tid==0) red[4] = red[0]+red[1]+red[2]+red[3];
  __syncthreads();
  float rstd = rsqrtf(red[4]*(1.f/DM_) + 1e-5f);
  for (int e=0;e<4;e++){
    int c = tid + 256*e;
    o[(size_t)row*DM_ + c] = g[c]*(v[e]-mu)*rstd + be[c];
  }
}

// ---------------- launch ----------------
extern "C" void kernel_launch(void* const* d_in, const int* in_sizes, int n_in,
                              void* d_out, int out_size, void* d_ws, size_t ws_size,
                              hipStream_t stream)
{
  const float* x    = (const float*)d_in[0];
  const float* mem  = (const float*)d_in[1];
  const float* pos  = (const float*)d_in[2];
  const float* pbu  = (const float*)d_in[3];
  const float* pbv  = (const float*)d_in[4];
  const float* wqkv = (const float*)d_in[5];
  const float* wrel = (const float*)d_in[6];
  const float* wo   = (const float*)d_in[7];
  const float* gam  = (const float*)d_in[8];
  const float* bet  = (const float*)d_in[9];
  float* out = (float*)d_out;

  char* w = (char*)d_ws;
  unsigned short* Kb    = (unsigned short*)(w + 0);          // 16,777,216
  unsigned short* relo  = (unsigned short*)(w + 16777216);   // 16,777,216
  unsigned short* wo16  = (unsigned short*)(w + 33554432);   //  2,097,152
  unsigned short* QUb   = (unsigned short*)(w + 35651584);   //  8,388,608
  unsigned short* QVb   = (unsigned short*)(w + 44040192);   //  8,388,608
  unsigned short* VT    = (unsigned short*)(w + 52428800);   // 16,777,216
  unsigned short* av16  = (unsigned short*)(w + 69206016);   //  8,388,608
  float*          yf    = (float*)(w + 77594624);            // 16,777,216
  unsigned short* c16   = (unsigned short*)(w + 94371840);   // 16,777,216
  unsigned short* pos16 = (unsigned short*)(w + 111149056);  // 16,777,216
  unsigned short* wq16  = (unsigned short*)(w + 127926272);  //  6,291,456
  unsigned short* wr16  = (unsigned short*)(w + 134217728);  //  2,097,152 -> total 136,314,880

  cast_all<<<10752, 256, 0, stream>>>(mem, x, pos, wqkv, wrel, wo,
                                      c16, pos16, wq16, wr16, wo16);

  // all four projection GEMMs (K / rel / Q+bias / V^T) in one dispatch
  gemm4<<<1792, 256, 0, stream>>>(c16, pos16, wq16, wr16, pbu, pbv,
                                  Kb, relo, QUb, QVb, VT);

  flash_attn4<<<dim3(64,16), 256, 0, stream>>>(QUb, QVb, Kb, VT, relo, av16);

  gemm_nt<<<dim3(8,32), 256, 0, stream>>>(av16, wo16, (void*)yf, x, 1024, 1024, 1);
  ln_kernel<<<4096, 256, 0, stream>>>(yf, gam, bet, out);
}